// Round 3
// baseline (838.630 us; speedup 1.0000x reference)
//
#include <hip/hip_runtime.h>

#define NN 50000
#define NE 800000

// ws layout (float-index offsets)
#define OFF_SE    0LL               // NN*16 f32  raw edge-attr sums per dst
#define OFF_H     (16LL*NN)         // NN*64 f32  hidden after BN+ReLU
#define OFF_Y2    (80LL*NN)         // NN*32 f32  H @ W2_msg[0:64,:]
#define OFF_CNT   (112LL*NN)        // NN ints
#define OFF_ROW   (113LL*NN)        // NN+1 ints
#define OFF_CUR   (115LL*NN)        // NN ints
#define OFF_RECS  (116LL*NN)        // NE int2 (src, eid) sorted by dst
#define OFF_FLAGS (148LL*NN)        // 2 ints
#define OFF_WT    (149LL*NN)        // folded f32 weights (14016 floats)
// WT sublayout
#define W_FW1X 0      // 64x64  (k*64+col), BN-folded
#define W_FW1S 4096   // 64x64
#define W_FW1E 8192   // 16x64
#define W_FB1M 9216   // 64
#define W_FB1S 9280   // 64
#define W_FW2M 9344   // 64x32  (k*32+j)
#define W_FW2E 11392  // 16x32
#define W_FW2S 11904  // 64x32
#define W_FB2M 13952  // 32
#define W_FB2S 13984  // 32

__device__ __forceinline__ float ldf(const void* p, long long i, int bf16) {
  if (bf16) {
    unsigned short u = ((const unsigned short*)p)[i];
    return __uint_as_float(((unsigned)u) << 16);
  }
  return ((const float*)p)[i];
}

__device__ __forceinline__ unsigned short f2bf(float f) {
  unsigned u = __float_as_uint(f);
  unsigned r = (u + 0x7fffu + ((u >> 16) & 1u)) >> 16;
  return (unsigned short)r;
}

__device__ __forceinline__ int ldidx(const void* p, long long i, int i64) {
  return i64 ? (int)((const long long*)p)[i] : ((const int*)p)[i];
}

__device__ __forceinline__ float bcast(float v, int k) {
  return __uint_as_float(__builtin_amdgcn_readlane(__float_as_uint(v), k));
}

__device__ __forceinline__ float bflo(unsigned u) {
  return __uint_as_float(u << 16);
}
__device__ __forceinline__ float bfhi(unsigned u) {
  return __uint_as_float(u & 0xffff0000u);
}

// ---------------- detect dtypes ----------------
__global__ void k_detect(const void* ei, const void* x, int* flags) {
  if (blockIdx.x == 0 && threadIdx.x == 0) {
    const int* p = (const int*)ei;
    int any = 0;
    for (int i = 0; i < 256; ++i) any |= p[2 * i + 1];
    flags[0] = (any == 0) ? 1 : 0;
    const unsigned short* q = (const unsigned short*)x;
    int cnt = 0;
    for (int i = 0; i < 256; ++i) {
      unsigned short w = q[2 * i];
      int e = (w >> 7) & 0xff;
      if (w == 0 || (e >= 110 && e <= 140)) cnt++;
    }
    flags[1] = (cnt >= 192) ? 1 : 0;
  }
}

// ---------------- fold weights to f32 (BN folded into layer-1) ----------------
__global__ __launch_bounds__(256) void k_prep(
    const void* __restrict__ W1_msg, const void* __restrict__ b1_msg,
    const void* __restrict__ W1_self, const void* __restrict__ b1_self,
    const void* __restrict__ gamma, const void* __restrict__ beta,
    const void* __restrict__ mean, const void* __restrict__ var,
    const void* __restrict__ W2_msg, const void* __restrict__ b2_msg,
    const void* __restrict__ W2_self, const void* __restrict__ b2_self,
    const int* __restrict__ flags, float* __restrict__ WT) {
  int bf = flags[1];
  int t = blockIdx.x * 256 + threadIdx.x;
  int stride = gridDim.x * 256;
  for (int i = t; i < 4096; i += stride) {
    int k = i >> 6, col = i & 63;
    float sc = ldf(gamma, col, bf) * rsqrtf(ldf(var, col, bf) + 1e-5f);
    WT[W_FW1X + i] = ldf(W1_msg, k * 64 + col, bf) * sc;
    WT[W_FW1S + i] = ldf(W1_self, k * 64 + col, bf) * sc;
  }
  for (int i = t; i < 1024; i += stride) {
    int k = i >> 6, col = i & 63;
    float sc = ldf(gamma, col, bf) * rsqrtf(ldf(var, col, bf) + 1e-5f);
    WT[W_FW1E + i] = ldf(W1_msg, (64 + k) * 64 + col, bf) * sc;
  }
  for (int i = t; i < 64; i += stride) {
    float sc = ldf(gamma, i, bf) * rsqrtf(ldf(var, i, bf) + 1e-5f);
    WT[W_FB1M + i] = ldf(b1_msg, i, bf) * sc;
    WT[W_FB1S + i] = ldf(b1_self, i, bf) * sc + ldf(beta, i, bf) - ldf(mean, i, bf) * sc;
  }
  for (int i = t; i < 2048; i += stride) {
    int k = i >> 5, j = i & 31;
    WT[W_FW2M + i] = ldf(W2_msg, k * 32 + j, bf);
    WT[W_FW2S + i] = ldf(W2_self, k * 32 + j, bf);
  }
  for (int i = t; i < 512; i += stride) {
    int k = i >> 5, j = i & 31;
    WT[W_FW2E + i] = ldf(W2_msg, (64 + k) * 32 + j, bf);
  }
  for (int i = t; i < 32; i += stride) {
    WT[W_FB2M + i] = ldf(b2_msg, i, bf);
    WT[W_FB2S + i] = ldf(b2_self, i, bf);
  }
}

// ---------------- CSR build ----------------
__global__ __launch_bounds__(256) void k_hist(const void* __restrict__ ei,
                                              const int* __restrict__ flags,
                                              int* __restrict__ counts) {
  long long e = (long long)blockIdx.x * 256 + threadIdx.x;
  if (e >= NE) return;
  int dst = ldidx(ei, NE + e, flags[0]);
  atomicAdd(&counts[dst], 1);
}

__global__ __launch_bounds__(1024) void k_scan(const int* __restrict__ counts,
                                               int* __restrict__ row_ptr,
                                               int* __restrict__ cursor) {
  __shared__ int sd[1024];
  const int CH = 49;  // 1024*49 >= 50000
  int t = threadIdx.x;
  int beg = t * CH;
  int end = beg + CH;
  if (beg > NN) beg = NN;
  if (end > NN) end = NN;
  int s = 0;
  for (int i = beg; i < end; ++i) s += counts[i];
  sd[t] = s;
  __syncthreads();
  for (int off = 1; off < 1024; off <<= 1) {
    int v = (t >= off) ? sd[t - off] : 0;
    __syncthreads();
    sd[t] += v;
    __syncthreads();
  }
  int run = sd[t] - s;
  for (int i = beg; i < end; ++i) {
    row_ptr[i] = run;
    cursor[i] = run;
    run += counts[i];
  }
  if (t == 1023) row_ptr[NN] = run;
}

__global__ __launch_bounds__(256) void k_fill(const void* __restrict__ ei,
                                              const int* __restrict__ flags,
                                              int* __restrict__ cursor,
                                              int2* __restrict__ recs) {
  long long e = (long long)blockIdx.x * 256 + threadIdx.x;
  if (e >= NE) return;
  int i64 = flags[0];
  int src = ldidx(ei, e, i64);
  int dst = ldidx(ei, NE + e, i64);
  int pos = atomicAdd(&cursor[dst], 1);
  recs[pos] = make_int2(src, (int)e);
}

// ---------------- layer 1: wide gather + GEMM + BN + ReLU + Y2 projection ----------------
__global__ __launch_bounds__(256, 2) void k_node1(
    const void* __restrict__ x, const int* __restrict__ row_ptr,
    const int2* __restrict__ recs, const void* __restrict__ ea,
    const float* __restrict__ WT, const int* __restrict__ flags,
    float* __restrict__ H, float* __restrict__ Y2, float* __restrict__ SeW) {
  int lane = threadIdx.x & 63;
  int bf = flags[1];
  // register-stage folded weights (col = lane)
  float w1x[64], w1s[64], w1e[16];
#pragma unroll
  for (int k = 0; k < 64; ++k) w1x[k] = WT[W_FW1X + k * 64 + lane];
#pragma unroll
  for (int k = 0; k < 64; ++k) w1s[k] = WT[W_FW1S + k * 64 + lane];
#pragma unroll
  for (int k = 0; k < 16; ++k) w1e[k] = WT[W_FW1E + k * 64 + lane];
  float fb1m = WT[W_FB1M + lane];
  float fb1s = WT[W_FB1S + lane];
  const float* FW2m = WT + W_FW2M;

  int g3 = lane >> 3, c8 = lane & 7;
  int g2 = lane >> 2, c4 = lane & 3;
  long long w0 = ((long long)blockIdx.x * blockDim.x + threadIdx.x) >> 6;
  long long nwaves = ((long long)gridDim.x * blockDim.x) >> 6;

  for (long long n = w0; n < NN; n += nwaves) {
    int beg = row_ptr[n], end = row_ptr[n + 1];
    float sxr[8] = {0.f, 0.f, 0.f, 0.f, 0.f, 0.f, 0.f, 0.f};
    float ser[4] = {0.f, 0.f, 0.f, 0.f};
    if (bf) {
      const unsigned short* xs = (const unsigned short*)x;
      const unsigned short* es = (const unsigned short*)ea;
      for (int base = beg; base < end; base += 64) {
        int m = end - base;
        if (m > 64) m = 64;
        int2 r = recs[base + (lane < m ? lane : m - 1)];
#pragma unroll
        for (int jj = 0; jj < 8; ++jj) {
          if (jj * 8 >= m) break;
          int eidx = jj * 8 + g3;
          int sv = __shfl(r.x, eidx, 64);
          uint4 w = *((const uint4*)(xs + ((long long)sv << 6)) + c8);
          float vf = eidx < m ? 1.0f : 0.0f;
          sxr[0] = fmaf(vf, bflo(w.x), sxr[0]);
          sxr[1] = fmaf(vf, bfhi(w.x), sxr[1]);
          sxr[2] = fmaf(vf, bflo(w.y), sxr[2]);
          sxr[3] = fmaf(vf, bfhi(w.y), sxr[3]);
          sxr[4] = fmaf(vf, bflo(w.z), sxr[4]);
          sxr[5] = fmaf(vf, bfhi(w.z), sxr[5]);
          sxr[6] = fmaf(vf, bflo(w.w), sxr[6]);
          sxr[7] = fmaf(vf, bfhi(w.w), sxr[7]);
        }
#pragma unroll
        for (int jj = 0; jj < 4; ++jj) {
          if (jj * 16 >= m) break;
          int eidx = jj * 16 + g2;
          int ev = __shfl(r.y, eidx, 64);
          uint2 e2 = *((const uint2*)(es + ((long long)ev << 4)) + c4);
          float vf = eidx < m ? 1.0f : 0.0f;
          ser[0] = fmaf(vf, bflo(e2.x), ser[0]);
          ser[1] = fmaf(vf, bfhi(e2.x), ser[1]);
          ser[2] = fmaf(vf, bflo(e2.y), ser[2]);
          ser[3] = fmaf(vf, bfhi(e2.y), ser[3]);
        }
      }
#pragma unroll
      for (int mk = 8; mk <= 32; mk <<= 1)
#pragma unroll
        for (int c = 0; c < 8; ++c) sxr[c] += __shfl_xor(sxr[c], mk, 64);
#pragma unroll
      for (int mk = 4; mk <= 32; mk <<= 1)
#pragma unroll
        for (int c = 0; c < 4; ++c) ser[c] += __shfl_xor(ser[c], mk, 64);
    } else {
      // f32 fallback (scalar per-edge), then convert layout
      float sx = 0.f, se = 0.f;
      const float* xf = (const float*)x;
      const float* ef = (const float*)ea;
      for (int base = beg; base < end; base += 64) {
        int m = end - base;
        if (m > 64) m = 64;
        int2 r = recs[base + (lane < m ? lane : m - 1)];
        for (int jv = 0; jv < m; ++jv) {
          int s0 = __builtin_amdgcn_readlane(r.x, jv);
          int e0 = __builtin_amdgcn_readlane(r.y, jv);
          sx += xf[(long long)s0 * 64 + lane];
          if (lane < 16) se += ef[(long long)e0 * 16 + lane];
        }
      }
#pragma unroll
      for (int c = 0; c < 8; ++c) sxr[c] = __shfl(sx, (lane & 7) * 8 + c, 64);
#pragma unroll
      for (int c = 0; c < 4; ++c) ser[c] = __shfl(se, (lane & 3) * 4 + c, 64);
    }
    float dg = (float)(end - beg);
    float xv = ldf(x, n * 64 + lane, bf);
    float a0 = fmaf(dg, fb1m, fb1s), a1 = 0.f, a2 = 0.f, a3 = 0.f;
#pragma unroll
    for (int k = 0; k < 64; k += 4) {
      a0 = fmaf(bcast(sxr[(k + 0) & 7], (k + 0) >> 3), w1x[k + 0],
                fmaf(bcast(xv, k + 0), w1s[k + 0], a0));
      a1 = fmaf(bcast(sxr[(k + 1) & 7], (k + 1) >> 3), w1x[k + 1],
                fmaf(bcast(xv, k + 1), w1s[k + 1], a1));
      a2 = fmaf(bcast(sxr[(k + 2) & 7], (k + 2) >> 3), w1x[k + 2],
                fmaf(bcast(xv, k + 2), w1s[k + 2], a2));
      a3 = fmaf(bcast(sxr[(k + 3) & 7], (k + 3) >> 3), w1x[k + 3],
                fmaf(bcast(xv, k + 3), w1s[k + 3], a3));
    }
#pragma unroll
    for (int k = 0; k < 16; k += 4) {
      a0 = fmaf(bcast(ser[(k + 0) & 3], (k + 0) >> 2), w1e[k + 0], a0);
      a1 = fmaf(bcast(ser[(k + 1) & 3], (k + 1) >> 2), w1e[k + 1], a1);
      a2 = fmaf(bcast(ser[(k + 2) & 3], (k + 2) >> 2), w1e[k + 2], a2);
      a3 = fmaf(bcast(ser[(k + 3) & 3], (k + 3) >> 2), w1e[k + 3], a3);
    }
    float h = fmaxf((a0 + a1) + (a2 + a3), 0.0f);
    H[n * 64 + lane] = h;
    // store raw se at col=lane (lane<16)
    {
      float v0 = __shfl(ser[0], lane >> 2, 64);
      float v1 = __shfl(ser[1], lane >> 2, 64);
      float v2 = __shfl(ser[2], lane >> 2, 64);
      float v3 = __shfl(ser[3], lane >> 2, 64);
      int c = lane & 3;
      float sv = c == 0 ? v0 : (c == 1 ? v1 : (c == 2 ? v2 : v3));
      if (lane < 16) SeW[n * 16 + lane] = sv;
    }
    // fused Y2 projection: Y2[n] = h-row @ W2_msg[0:64,:]
    int j = lane & 31;
    float y0 = 0.f, y1 = 0.f, y2 = 0.f, y3 = 0.f;
#pragma unroll
    for (int k = 0; k < 64; k += 4) {
      y0 = fmaf(bcast(h, k + 0), FW2m[(k + 0) * 32 + j], y0);
      y1 = fmaf(bcast(h, k + 1), FW2m[(k + 1) * 32 + j], y1);
      y2 = fmaf(bcast(h, k + 2), FW2m[(k + 2) * 32 + j], y2);
      y3 = fmaf(bcast(h, k + 3), FW2m[(k + 3) * 32 + j], y3);
    }
    if (lane < 32) Y2[n * 32 + j] = (y0 + y1) + (y2 + y3);
  }
}

// ---------------- layer 2: wide Y2 gather + GEMM -> out ----------------
__global__ __launch_bounds__(256, 2) void k_node2(
    const float* __restrict__ H, const float* __restrict__ SeW,
    const int* __restrict__ row_ptr, const int2* __restrict__ recs,
    const float* __restrict__ Y2, const float* __restrict__ WT,
    const int* __restrict__ flags, void* __restrict__ out) {
  int lane = threadIdx.x & 63;
  int bf = flags[1];
  int j = lane & 31;
  float w2s[64], w2e[16];
#pragma unroll
  for (int k = 0; k < 64; ++k) w2s[k] = WT[W_FW2S + k * 32 + j];
#pragma unroll
  for (int k = 0; k < 16; ++k) w2e[k] = WT[W_FW2E + k * 32 + j];
  float fb2m = WT[W_FB2M + j];
  float fb2s = WT[W_FB2S + j];
  int g3 = lane >> 3, c8 = lane & 7;
  long long w0 = ((long long)blockIdx.x * blockDim.x + threadIdx.x) >> 6;
  long long nwaves = ((long long)gridDim.x * blockDim.x) >> 6;
  for (long long n = w0; n < NN; n += nwaves) {
    int beg = row_ptr[n], end = row_ptr[n + 1];
    float s2r[4] = {0.f, 0.f, 0.f, 0.f};
    for (int base = beg; base < end; base += 64) {
      int m = end - base;
      if (m > 64) m = 64;
      int2 r = recs[base + (lane < m ? lane : m - 1)];
#pragma unroll
      for (int jj = 0; jj < 8; ++jj) {
        if (jj * 8 >= m) break;
        int eidx = jj * 8 + g3;
        int sv = __shfl(r.x, eidx, 64);
        float4 y = *((const float4*)Y2 + ((long long)sv * 8 + c8));
        float vf = eidx < m ? 1.0f : 0.0f;
        s2r[0] = fmaf(vf, y.x, s2r[0]);
        s2r[1] = fmaf(vf, y.y, s2r[1]);
        s2r[2] = fmaf(vf, y.z, s2r[2]);
        s2r[3] = fmaf(vf, y.w, s2r[3]);
      }
    }
#pragma unroll
    for (int mk = 8; mk <= 32; mk <<= 1)
#pragma unroll
      for (int c = 0; c < 4; ++c) s2r[c] += __shfl_xor(s2r[c], mk, 64);
    // remap partial layout (col=(lane&7)*4+c) to col=j
    float v0 = __shfl(s2r[0], j >> 2, 64);
    float v1 = __shfl(s2r[1], j >> 2, 64);
    float v2 = __shfl(s2r[2], j >> 2, 64);
    float v3 = __shfl(s2r[3], j >> 2, 64);
    int cc = j & 3;
    float s2 = cc == 0 ? v0 : (cc == 1 ? v1 : (cc == 2 ? v2 : v3));
    float hv = H[n * 64 + lane];
    float se = (lane < 16) ? SeW[n * 16 + lane] : 0.0f;
    float dg = (float)(end - beg);
    float a0 = fmaf(dg, fb2m, fb2s) + s2, a1 = 0.f, a2 = 0.f, a3 = 0.f;
#pragma unroll
    for (int k = 0; k < 64; k += 4) {
      a0 = fmaf(bcast(hv, k + 0), w2s[k + 0], a0);
      a1 = fmaf(bcast(hv, k + 1), w2s[k + 1], a1);
      a2 = fmaf(bcast(hv, k + 2), w2s[k + 2], a2);
      a3 = fmaf(bcast(hv, k + 3), w2s[k + 3], a3);
    }
#pragma unroll
    for (int k = 0; k < 16; k += 4) {
      a0 = fmaf(bcast(se, k + 0), w2e[k + 0], a0);
      a1 = fmaf(bcast(se, k + 1), w2e[k + 1], a1);
      a2 = fmaf(bcast(se, k + 2), w2e[k + 2], a2);
      a3 = fmaf(bcast(se, k + 3), w2e[k + 3], a3);
    }
    float o = (a0 + a1) + (a2 + a3);
    if (lane < 32) {
      if (bf)
        ((unsigned short*)out)[n * 32 + j] = f2bf(o);
      else
        ((float*)out)[n * 32 + j] = o;
    }
  }
}

extern "C" void kernel_launch(void* const* d_in, const int* in_sizes, int n_in,
                              void* d_out, int out_size, void* d_ws, size_t ws_size,
                              hipStream_t stream) {
  const void* x = d_in[0];
  const void* ei = d_in[1];
  const void* ea = d_in[2];
  const void* W1_msg = d_in[3];
  const void* b1_msg = d_in[4];
  const void* W1_self = d_in[5];
  const void* b1_self = d_in[6];
  const void* gamma = d_in[7];
  const void* beta = d_in[8];
  const void* mean = d_in[9];
  const void* var = d_in[10];
  const void* W2_msg = d_in[11];
  const void* b2_msg = d_in[12];
  const void* W2_self = d_in[13];
  const void* b2_self = d_in[14];

  float* ws = (float*)d_ws;
  float* SeW = ws + OFF_SE;
  float* H = ws + OFF_H;
  float* Y2 = ws + OFF_Y2;
  int* counts = (int*)(ws + OFF_CNT);
  int* row_ptr = (int*)(ws + OFF_ROW);
  int* cursor = (int*)(ws + OFF_CUR);
  int2* recs = (int2*)(ws + OFF_RECS);
  int* flags = (int*)(ws + OFF_FLAGS);
  float* WT = ws + OFF_WT;

  hipLaunchKernelGGL(k_detect, dim3(1), dim3(64), 0, stream, ei, x, flags);
  hipMemsetAsync(counts, 0, (size_t)NN * sizeof(int), stream);
  hipLaunchKernelGGL(k_prep, dim3(32), dim3(256), 0, stream, W1_msg, b1_msg, W1_self,
                     b1_self, gamma, beta, mean, var, W2_msg, b2_msg, W2_self, b2_self,
                     flags, WT);

  int eblocks = (NE + 255) / 256;
  hipLaunchKernelGGL(k_hist, dim3(eblocks), dim3(256), 0, stream, ei, flags, counts);
  hipLaunchKernelGGL(k_scan, dim3(1), dim3(1024), 0, stream, counts, row_ptr, cursor);
  hipLaunchKernelGGL(k_fill, dim3(eblocks), dim3(256), 0, stream, ei, flags, cursor, recs);

  hipLaunchKernelGGL(k_node1, dim3(1536), dim3(256), 0, stream, x, row_ptr, recs, ea, WT,
                     flags, H, Y2, SeW);
  hipLaunchKernelGGL(k_node2, dim3(1536), dim3(256), 0, stream, H, SeW, row_ptr, recs,
                     Y2, WT, flags, d_out);
}

// Round 4
// 495.552 us; speedup vs baseline: 1.6923x; 1.6923x over previous
//
#include <hip/hip_runtime.h>

#define NN 50000
#define NE 800000
#define NB 6250  // NN/8 batches of 8 nodes

// ws layout (float-index offsets)
#define OFF_SE    0LL                 // NN*16 f32 raw edge-attr sums
#define OFF_H     (16LL*NN)           // NN*64 f32 hidden after BN+ReLU
#define OFF_Y2    (80LL*NN)           // NN*32 f32 H @ W2_msg[0:64,:]
#define OFF_SX    (112LL*NN)          // NN*64 f32 x-row sums (S2 aliases this later)
#define OFF_CNT   (176LL*NN)          // NN ints
#define OFF_ROW   (177LL*NN)          // NN+1 ints
#define OFF_CUR   (179LL*NN)          // NN ints
#define OFF_RECS  (180LL*NN)          // NE int2
#define OFF_FLAGS (212LL*NN)          // 2 ints
#define OFF_WT    (212LL*NN + 16)     // 14016 f32 folded weights
// WT sublayout (f32)
#define W_FW1X 0      // 64x64 (k*64+col) BN-folded
#define W_FW1S 4096   // 64x64
#define W_FW1E 8192   // 16x64
#define W_FB1M 9216   // 64
#define W_FB1S 9280   // 64
#define W_FW2M 9344   // 64x32 (k*32+j)
#define W_FW2E 11392  // 16x32
#define W_FW2S 11904  // 64x32
#define W_FB2M 13952  // 32
#define W_FB2S 13984  // 32

__device__ __forceinline__ float ldf(const void* p, long long i, int bf16) {
  if (bf16) {
    unsigned short u = ((const unsigned short*)p)[i];
    return __uint_as_float(((unsigned)u) << 16);
  }
  return ((const float*)p)[i];
}

__device__ __forceinline__ unsigned short f2bf(float f) {
  unsigned u = __float_as_uint(f);
  unsigned r = (u + 0x7fffu + ((u >> 16) & 1u)) >> 16;
  return (unsigned short)r;
}

__device__ __forceinline__ int ldidx(const void* p, long long i, int i64) {
  return i64 ? (int)((const long long*)p)[i] : ((const int*)p)[i];
}

__device__ __forceinline__ float bcast(float v, int k) {
  return __uint_as_float(__builtin_amdgcn_readlane(__float_as_uint(v), k));
}

__device__ __forceinline__ float bflo(unsigned u) { return __uint_as_float(u << 16); }
__device__ __forceinline__ float bfhi(unsigned u) { return __uint_as_float(u & 0xffff0000u); }

// ---------------- detect dtypes ----------------
__global__ void k_detect(const void* ei, const void* x, int* flags) {
  if (blockIdx.x == 0 && threadIdx.x == 0) {
    const int* p = (const int*)ei;
    int any = 0;
    for (int i = 0; i < 256; ++i) any |= p[2 * i + 1];
    flags[0] = (any == 0) ? 1 : 0;
    const unsigned short* q = (const unsigned short*)x;
    int cnt = 0;
    for (int i = 0; i < 256; ++i) {
      unsigned short w = q[2 * i];
      int e = (w >> 7) & 0xff;
      if (w == 0 || (e >= 110 && e <= 140)) cnt++;
    }
    flags[1] = (cnt >= 192) ? 1 : 0;
  }
}

// ---------------- fold weights to f32 (BN folded into layer 1) ----------------
__global__ __launch_bounds__(256) void k_prep(
    const void* __restrict__ W1_msg, const void* __restrict__ b1_msg,
    const void* __restrict__ W1_self, const void* __restrict__ b1_self,
    const void* __restrict__ gamma, const void* __restrict__ beta,
    const void* __restrict__ mean, const void* __restrict__ var,
    const void* __restrict__ W2_msg, const void* __restrict__ b2_msg,
    const void* __restrict__ W2_self, const void* __restrict__ b2_self,
    const int* __restrict__ flags, float* __restrict__ WT) {
  int bf = flags[1];
  int t = blockIdx.x * 256 + threadIdx.x;
  int stride = gridDim.x * 256;
  for (int i = t; i < 4096; i += stride) {
    int k = i >> 6, col = i & 63;
    float sc = ldf(gamma, col, bf) * rsqrtf(ldf(var, col, bf) + 1e-5f);
    WT[W_FW1X + i] = ldf(W1_msg, k * 64 + col, bf) * sc;
    WT[W_FW1S + i] = ldf(W1_self, k * 64 + col, bf) * sc;
  }
  for (int i = t; i < 1024; i += stride) {
    int k = i >> 6, col = i & 63;
    float sc = ldf(gamma, col, bf) * rsqrtf(ldf(var, col, bf) + 1e-5f);
    WT[W_FW1E + i] = ldf(W1_msg, (64 + k) * 64 + col, bf) * sc;
  }
  for (int i = t; i < 64; i += stride) {
    float sc = ldf(gamma, i, bf) * rsqrtf(ldf(var, i, bf) + 1e-5f);
    WT[W_FB1M + i] = ldf(b1_msg, i, bf) * sc;
    WT[W_FB1S + i] = ldf(b1_self, i, bf) * sc + ldf(beta, i, bf) - ldf(mean, i, bf) * sc;
  }
  for (int i = t; i < 2048; i += stride) {
    int k = i >> 5, j = i & 31;
    WT[W_FW2M + i] = ldf(W2_msg, k * 32 + j, bf);
    WT[W_FW2S + i] = ldf(W2_self, k * 32 + j, bf);
  }
  for (int i = t; i < 512; i += stride) {
    int k = i >> 5, j = i & 31;
    WT[W_FW2E + i] = ldf(W2_msg, (64 + k) * 32 + j, bf);
  }
  for (int i = t; i < 32; i += stride) {
    WT[W_FB2M + i] = ldf(b2_msg, i, bf);
    WT[W_FB2S + i] = ldf(b2_self, i, bf);
  }
}

// ---------------- CSR build ----------------
__global__ __launch_bounds__(256) void k_hist(const void* __restrict__ ei,
                                              const int* __restrict__ flags,
                                              int* __restrict__ counts) {
  long long e = (long long)blockIdx.x * 256 + threadIdx.x;
  if (e >= NE) return;
  int dst = ldidx(ei, NE + e, flags[0]);
  atomicAdd(&counts[dst], 1);
}

__global__ __launch_bounds__(1024) void k_scan(const int* __restrict__ counts,
                                               int* __restrict__ row_ptr,
                                               int* __restrict__ cursor) {
  __shared__ int sd[1024];
  const int CH = 49;  // 1024*49 >= 50000
  int t = threadIdx.x;
  int beg = t * CH, end = beg + CH;
  if (beg > NN) beg = NN;
  if (end > NN) end = NN;
  int s = 0;
  for (int i = beg; i < end; ++i) s += counts[i];
  sd[t] = s;
  __syncthreads();
  for (int off = 1; off < 1024; off <<= 1) {
    int v = (t >= off) ? sd[t - off] : 0;
    __syncthreads();
    sd[t] += v;
    __syncthreads();
  }
  int run = sd[t] - s;
  for (int i = beg; i < end; ++i) {
    row_ptr[i] = run;
    cursor[i] = run;
    run += counts[i];
  }
  if (t == 1023) row_ptr[NN] = run;
}

__global__ __launch_bounds__(256) void k_fill(const void* __restrict__ ei,
                                              const int* __restrict__ flags,
                                              int* __restrict__ cursor,
                                              int2* __restrict__ recs) {
  long long e = (long long)blockIdx.x * 256 + threadIdx.x;
  if (e >= NE) return;
  int i64 = flags[0];
  int src = ldidx(ei, e, i64);
  int dst = ldidx(ei, NE + e, i64);
  int pos = atomicAdd(&cursor[dst], 1);
  recs[pos] = make_int2(src, (int)e);
}

// ---------------- gather 1: per-group (8 lanes/node) pull; no cross-lane ops ----------------
__global__ __launch_bounds__(256) void k_gather1(
    const void* __restrict__ x, const void* __restrict__ ea,
    const int* __restrict__ row_ptr, const int2* __restrict__ recs,
    const int* __restrict__ flags, float* __restrict__ Sx, float* __restrict__ Se) {
  int lane = threadIdx.x & 63;
  int g = lane >> 3, c = lane & 7;
  int bf = flags[1];
  long long wid = ((long long)blockIdx.x * blockDim.x + threadIdx.x) >> 6;
  long long nw = ((long long)gridDim.x * blockDim.x) >> 6;
  for (long long b = wid; b < NB; b += nw) {
    int n = (int)(b * 8 + g);
    int beg = row_ptr[n];
    int deg = row_ptr[n + 1] - beg;
    float a0 = 0.f, a1 = 0.f, a2 = 0.f, a3 = 0.f, a4 = 0.f, a5 = 0.f, a6 = 0.f, a7 = 0.f;
    float e0 = 0.f, e1 = 0.f, e2 = 0.f, e3 = 0.f;
    if (bf) {
      const unsigned short* xs = (const unsigned short*)x;
      const unsigned short* es = (const unsigned short*)ea;
      for (int t = 0; __ballot(t < deg) != 0ull; ++t) {
        if (t < deg) {
          int2 r = recs[beg + t];
          uint4 w = *((const uint4*)(xs + ((long long)r.x << 6)) + c);
          a0 += bflo(w.x); a1 += bfhi(w.x);
          a2 += bflo(w.y); a3 += bfhi(w.y);
          a4 += bflo(w.z); a5 += bfhi(w.z);
          a6 += bflo(w.w); a7 += bfhi(w.w);
          if (c < 4) {
            uint2 q = *((const uint2*)(es + ((long long)r.y << 4)) + c);
            e0 += bflo(q.x); e1 += bfhi(q.x);
            e2 += bflo(q.y); e3 += bfhi(q.y);
          }
        }
      }
    } else {
      const float* xf = (const float*)x;
      const float* ef = (const float*)ea;
      for (int t = 0; __ballot(t < deg) != 0ull; ++t) {
        if (t < deg) {
          int2 r = recs[beg + t];
          float4 w0 = *((const float4*)(xf + ((long long)r.x << 6)) + c * 2);
          float4 w1 = *((const float4*)(xf + ((long long)r.x << 6)) + c * 2 + 1);
          a0 += w0.x; a1 += w0.y; a2 += w0.z; a3 += w0.w;
          a4 += w1.x; a5 += w1.y; a6 += w1.z; a7 += w1.w;
          if (c < 4) {
            float4 q = *((const float4*)(ef + ((long long)r.y << 4)) + c);
            e0 += q.x; e1 += q.y; e2 += q.z; e3 += q.w;
          }
        }
      }
    }
    float4* sxp = (float4*)(Sx + (long long)n * 64 + c * 8);
    sxp[0] = make_float4(a0, a1, a2, a3);
    sxp[1] = make_float4(a4, a5, a6, a7);
    if (c < 4) *(float4*)(Se + (long long)n * 16 + c * 4) = make_float4(e0, e1, e2, e3);
  }
}

// ---------------- gemm 1: batch-8 nodes/wave, LDS weights -> H, Y2 ----------------
__global__ __launch_bounds__(256) void k_gemm1(
    const void* __restrict__ x, const float* __restrict__ Sx,
    const float* __restrict__ Se, const int* __restrict__ row_ptr,
    const float* __restrict__ WT, const int* __restrict__ flags,
    float* __restrict__ H, float* __restrict__ Y2) {
  __shared__ float sw[11392];  // FW1X|FW1S|FW1E|FB1M|FB1S|FW2M (contiguous in WT)
  for (int i = threadIdx.x; i < 11392; i += 256) sw[i] = WT[i];
  __syncthreads();
  const float* swX = sw + W_FW1X;
  const float* swS = sw + W_FW1S;
  const float* swE = sw + W_FW1E;
  const float* swM = sw + W_FW2M;
  int lane = threadIdx.x & 63;
  int bf = flags[1];
  float fb1m = sw[W_FB1M + lane];
  float fb1s = sw[W_FB1S + lane];
  int j = lane & 31;
  long long wid = ((long long)blockIdx.x * blockDim.x + threadIdx.x) >> 6;
  long long nw = ((long long)gridDim.x * blockDim.x) >> 6;
  for (long long b = wid; b < NB; b += nw) {
    long long n0 = b * 8;
    float sxv[8], xv[8], sev[8], acc[8];
#pragma unroll
    for (int g = 0; g < 8; ++g) {
      long long n = n0 + g;
      sxv[g] = Sx[n * 64 + lane];
      xv[g] = ldf(x, n * 64 + lane, bf);
      sev[g] = Se[n * 16 + (lane & 15)];
      float dg = (float)(row_ptr[n + 1] - row_ptr[n]);
      acc[g] = fmaf(dg, fb1m, fb1s);
    }
#pragma unroll 4
    for (int k = 0; k < 64; ++k) {
      float wx = swX[k * 64 + lane];
      float wsf = swS[k * 64 + lane];
#pragma unroll
      for (int g = 0; g < 8; ++g) {
        acc[g] = fmaf(bcast(sxv[g], k), wx, acc[g]);
        acc[g] = fmaf(bcast(xv[g], k), wsf, acc[g]);
      }
    }
#pragma unroll 4
    for (int k = 0; k < 16; ++k) {
      float wel = swE[k * 64 + lane];
#pragma unroll
      for (int g = 0; g < 8; ++g) acc[g] = fmaf(bcast(sev[g], k), wel, acc[g]);
    }
#pragma unroll
    for (int g = 0; g < 8; ++g) {
      acc[g] = fmaxf(acc[g], 0.0f);
      H[(n0 + g) * 64 + lane] = acc[g];
    }
    // Y2 = H @ W2_msg[0:64,:]
    float y[8];
#pragma unroll
    for (int g = 0; g < 8; ++g) y[g] = 0.f;
#pragma unroll 4
    for (int k = 0; k < 64; ++k) {
      float wm = swM[k * 32 + j];
#pragma unroll
      for (int g = 0; g < 8; ++g) y[g] = fmaf(bcast(acc[g], k), wm, y[g]);
    }
    if (lane < 32) {
#pragma unroll
      for (int g = 0; g < 8; ++g) Y2[(n0 + g) * 32 + j] = y[g];
    }
  }
}

// ---------------- gather 2: per-group pull of Y2 rows -> S2 ----------------
__global__ __launch_bounds__(256) void k_gather2(
    const float* __restrict__ Y2, const int* __restrict__ row_ptr,
    const int2* __restrict__ recs, float* __restrict__ S2) {
  int lane = threadIdx.x & 63;
  int g = lane >> 3, c = lane & 7;
  long long wid = ((long long)blockIdx.x * blockDim.x + threadIdx.x) >> 6;
  long long nw = ((long long)gridDim.x * blockDim.x) >> 6;
  for (long long b = wid; b < NB; b += nw) {
    int n = (int)(b * 8 + g);
    int beg = row_ptr[n];
    int deg = row_ptr[n + 1] - beg;
    float s0 = 0.f, s1 = 0.f, s2 = 0.f, s3 = 0.f;
    for (int t = 0; __ballot(t < deg) != 0ull; ++t) {
      if (t < deg) {
        int2 r = recs[beg + t];
        float4 y = *((const float4*)(Y2 + (long long)r.x * 32) + c);
        s0 += y.x; s1 += y.y; s2 += y.z; s3 += y.w;
      }
    }
    *(float4*)(S2 + (long long)n * 32 + c * 4) = make_float4(s0, s1, s2, s3);
  }
}

// ---------------- gemm 2: batch-8 nodes/wave -> out ----------------
__global__ __launch_bounds__(256) void k_gemm2(
    const float* __restrict__ H, const float* __restrict__ Se,
    const float* __restrict__ S2, const int* __restrict__ row_ptr,
    const float* __restrict__ WT, const int* __restrict__ flags,
    void* __restrict__ out) {
  __shared__ float sw[2624];  // FW2E|FW2S|FB2M|FB2S (contiguous in WT at 11392)
  for (int i = threadIdx.x; i < 2624; i += 256) sw[i] = WT[11392 + i];
  __syncthreads();
  const float* swE = sw;                   // 16x32
  const float* swS = sw + 512;             // 64x32
  int lane = threadIdx.x & 63;
  int bf = flags[1];
  int j = lane & 31;
  float fb2m = sw[2560 + j];
  float fb2s = sw[2592 + j];
  long long wid = ((long long)blockIdx.x * blockDim.x + threadIdx.x) >> 6;
  long long nw = ((long long)gridDim.x * blockDim.x) >> 6;
  for (long long b = wid; b < NB; b += nw) {
    long long n0 = b * 8;
    float hv[8], sev[8], acc[8];
#pragma unroll
    for (int g = 0; g < 8; ++g) {
      long long n = n0 + g;
      hv[g] = H[n * 64 + lane];
      sev[g] = Se[n * 16 + (lane & 15)];
      float dg = (float)(row_ptr[n + 1] - row_ptr[n]);
      acc[g] = fmaf(dg, fb2m, fb2s) + S2[n * 32 + j];
    }
#pragma unroll 4
    for (int k = 0; k < 64; ++k) {
      float w = swS[k * 32 + j];
#pragma unroll
      for (int g = 0; g < 8; ++g) acc[g] = fmaf(bcast(hv[g], k), w, acc[g]);
    }
#pragma unroll 4
    for (int k = 0; k < 16; ++k) {
      float w = swE[k * 32 + j];
#pragma unroll
      for (int g = 0; g < 8; ++g) acc[g] = fmaf(bcast(sev[g], k), w, acc[g]);
    }
    if (lane < 32) {
      if (bf) {
#pragma unroll
        for (int g = 0; g < 8; ++g)
          ((unsigned short*)out)[(n0 + g) * 32 + j] = f2bf(acc[g]);
      } else {
#pragma unroll
        for (int g = 0; g < 8; ++g) ((float*)out)[(n0 + g) * 32 + j] = acc[g];
      }
    }
  }
}

extern "C" void kernel_launch(void* const* d_in, const int* in_sizes, int n_in,
                              void* d_out, int out_size, void* d_ws, size_t ws_size,
                              hipStream_t stream) {
  const void* x = d_in[0];
  const void* ei = d_in[1];
  const void* ea = d_in[2];
  const void* W1_msg = d_in[3];
  const void* b1_msg = d_in[4];
  const void* W1_self = d_in[5];
  const void* b1_self = d_in[6];
  const void* gamma = d_in[7];
  const void* beta = d_in[8];
  const void* mean = d_in[9];
  const void* var = d_in[10];
  const void* W2_msg = d_in[11];
  const void* b2_msg = d_in[12];
  const void* W2_self = d_in[13];
  const void* b2_self = d_in[14];

  float* ws = (float*)d_ws;
  float* Se = ws + OFF_SE;
  float* H = ws + OFF_H;
  float* Y2 = ws + OFF_Y2;
  float* Sx = ws + OFF_SX;
  float* S2 = ws + OFF_SX;  // S2 reuses Sx space (Sx dead after k_gemm1)
  int* counts = (int*)(ws + OFF_CNT);
  int* row_ptr = (int*)(ws + OFF_ROW);
  int* cursor = (int*)(ws + OFF_CUR);
  int2* recs = (int2*)(ws + OFF_RECS);
  int* flags = (int*)(ws + OFF_FLAGS);
  float* WT = ws + OFF_WT;

  hipLaunchKernelGGL(k_detect, dim3(1), dim3(64), 0, stream, ei, x, flags);
  hipMemsetAsync(counts, 0, (size_t)NN * sizeof(int), stream);
  hipLaunchKernelGGL(k_prep, dim3(32), dim3(256), 0, stream, W1_msg, b1_msg, W1_self,
                     b1_self, gamma, beta, mean, var, W2_msg, b2_msg, W2_self, b2_self,
                     flags, WT);

  int eblocks = (NE + 255) / 256;
  hipLaunchKernelGGL(k_hist, dim3(eblocks), dim3(256), 0, stream, ei, flags, counts);
  hipLaunchKernelGGL(k_scan, dim3(1), dim3(1024), 0, stream, counts, row_ptr, cursor);
  hipLaunchKernelGGL(k_fill, dim3(eblocks), dim3(256), 0, stream, ei, flags, cursor, recs);

  int nblocks = (NB + 3) / 4;  // 4 waves/block, 1 batch/wave minimum
  hipLaunchKernelGGL(k_gather1, dim3(nblocks), dim3(256), 0, stream, x, ea, row_ptr,
                     recs, flags, Sx, Se);
  hipLaunchKernelGGL(k_gemm1, dim3(nblocks), dim3(256), 0, stream, x, Sx, Se, row_ptr,
                     WT, flags, H, Y2);
  hipLaunchKernelGGL(k_gather2, dim3(nblocks), dim3(256), 0, stream, Y2, row_ptr, recs,
                     S2);
  hipLaunchKernelGGL(k_gemm2, dim3(nblocks), dim3(256), 0, stream, H, Se, S2, row_ptr,
                     WT, flags, d_out);
}

// Round 5
// 376.163 us; speedup vs baseline: 2.2294x; 1.3174x over previous
//
#include <hip/hip_runtime.h>

#define NN 50000
#define NE 800000
#define NB 6250        // NN/8 batches of 8 nodes
#define SCB 49         // ceil(NN/1024) scan blocks

// ws layout (float-index offsets)
#define OFF_SE    0LL                 // NN*16 f32 raw edge-attr sums
#define OFF_H     (16LL*NN)           // NN*64 f32 hidden after BN+ReLU
#define OFF_Y2    (80LL*NN)           // NN*32 f32 H @ W2_msg[0:64,:]
#define OFF_SX    (112LL*NN)          // NN*64 f32 x-row sums (S2 aliases later)
#define OFF_CNT   (176LL*NN)          // NN ints
#define OFF_ROW   (177LL*NN)          // NN+1 ints
#define OFF_CUR   (179LL*NN)          // NN ints
#define OFF_RECS  (180LL*NN)          // NE int2
#define OFF_FLAGS (212LL*NN)          // 2 ints (16 floats reserved)
#define OFF_BS    (212LL*NN + 16)     // 64 ints block sums
#define OFF_BO    (212LL*NN + 80)     // 64 ints block offsets
#define OFF_WT    (212LL*NN + 144)    // 14016 f32 folded weights
// WT sublayout (f32)
#define W_FW1X 0      // 64x64 (k*64+col) BN-folded
#define W_FW1S 4096   // 64x64
#define W_FW1E 8192   // 16x64
#define W_FB1M 9216   // 64
#define W_FB1S 9280   // 64
#define W_FW2M 9344   // 64x32 (k*32+j)
#define W_FW2E 11392  // 16x32
#define W_FW2S 11904  // 64x32
#define W_FB2M 13952  // 32
#define W_FB2S 13984  // 32

__device__ __forceinline__ float ldf(const void* p, long long i, int bf16) {
  if (bf16) {
    unsigned short u = ((const unsigned short*)p)[i];
    return __uint_as_float(((unsigned)u) << 16);
  }
  return ((const float*)p)[i];
}

__device__ __forceinline__ unsigned short f2bf(float f) {
  unsigned u = __float_as_uint(f);
  unsigned r = (u + 0x7fffu + ((u >> 16) & 1u)) >> 16;
  return (unsigned short)r;
}

__device__ __forceinline__ int ldidx(const void* p, long long i, int i64) {
  return i64 ? (int)((const long long*)p)[i] : ((const int*)p)[i];
}

__device__ __forceinline__ float bcast(float v, int k) {
  return __uint_as_float(__builtin_amdgcn_readlane(__float_as_uint(v), k));
}

__device__ __forceinline__ float bflo(unsigned u) { return __uint_as_float(u << 16); }
__device__ __forceinline__ float bfhi(unsigned u) { return __uint_as_float(u & 0xffff0000u); }

// ---------------- detect dtypes (wave-parallel) ----------------
__global__ void k_detect(const void* ei, const void* x, int* flags) {
  int lane = threadIdx.x & 63;
  const int* p = (const int*)ei;
  int any = 0;
  for (int i = lane; i < 256; i += 64) any |= p[2 * i + 1];
  unsigned long long anyb = __ballot(any != 0);
  const unsigned short* q = (const unsigned short*)x;
  int cnt = 0;
  for (int i = lane; i < 256; i += 64) {
    unsigned short w = q[2 * i];
    int e = (w >> 7) & 0xff;
    if (w == 0 || (e >= 110 && e <= 140)) cnt++;
  }
  for (int m = 1; m < 64; m <<= 1) cnt += __shfl_xor(cnt, m, 64);
  if (lane == 0) {
    flags[0] = (anyb == 0ull) ? 1 : 0;
    flags[1] = (cnt >= 192) ? 1 : 0;
  }
}

// ---------------- fold weights to f32 (BN folded into layer 1) ----------------
__global__ __launch_bounds__(256) void k_prep(
    const void* __restrict__ W1_msg, const void* __restrict__ b1_msg,
    const void* __restrict__ W1_self, const void* __restrict__ b1_self,
    const void* __restrict__ gamma, const void* __restrict__ beta,
    const void* __restrict__ mean, const void* __restrict__ var,
    const void* __restrict__ W2_msg, const void* __restrict__ b2_msg,
    const void* __restrict__ W2_self, const void* __restrict__ b2_self,
    const int* __restrict__ flags, float* __restrict__ WT) {
  int bf = flags[1];
  int t = blockIdx.x * 256 + threadIdx.x;
  int stride = gridDim.x * 256;
  for (int i = t; i < 4096; i += stride) {
    int k = i >> 6, col = i & 63;
    float sc = ldf(gamma, col, bf) * rsqrtf(ldf(var, col, bf) + 1e-5f);
    WT[W_FW1X + i] = ldf(W1_msg, k * 64 + col, bf) * sc;
    WT[W_FW1S + i] = ldf(W1_self, k * 64 + col, bf) * sc;
  }
  for (int i = t; i < 1024; i += stride) {
    int k = i >> 6, col = i & 63;
    float sc = ldf(gamma, col, bf) * rsqrtf(ldf(var, col, bf) + 1e-5f);
    WT[W_FW1E + i] = ldf(W1_msg, (64 + k) * 64 + col, bf) * sc;
  }
  for (int i = t; i < 64; i += stride) {
    float sc = ldf(gamma, i, bf) * rsqrtf(ldf(var, i, bf) + 1e-5f);
    WT[W_FB1M + i] = ldf(b1_msg, i, bf) * sc;
    WT[W_FB1S + i] = ldf(b1_self, i, bf) * sc + ldf(beta, i, bf) - ldf(mean, i, bf) * sc;
  }
  for (int i = t; i < 2048; i += stride) {
    int k = i >> 5, j = i & 31;
    WT[W_FW2M + i] = ldf(W2_msg, k * 32 + j, bf);
    WT[W_FW2S + i] = ldf(W2_self, k * 32 + j, bf);
  }
  for (int i = t; i < 512; i += stride) {
    int k = i >> 5, j = i & 31;
    WT[W_FW2E + i] = ldf(W2_msg, (64 + k) * 32 + j, bf);
  }
  for (int i = t; i < 32; i += stride) {
    WT[W_FB2M + i] = ldf(b2_msg, i, bf);
    WT[W_FB2S + i] = ldf(b2_self, i, bf);
  }
}

// ---------------- CSR build ----------------
__global__ __launch_bounds__(256) void k_hist(const void* __restrict__ ei,
                                              const int* __restrict__ flags,
                                              int* __restrict__ counts) {
  long long e = (long long)blockIdx.x * 256 + threadIdx.x;
  if (e >= NE) return;
  int dst = ldidx(ei, NE + e, flags[0]);
  atomicAdd(&counts[dst], 1);
}

// scan phase A: per-block sums (coalesced)
__global__ __launch_bounds__(1024) void k_scanA(const int* __restrict__ counts,
                                                int* __restrict__ bs) {
  __shared__ int sd[1024];
  int t = threadIdx.x;
  int i = blockIdx.x * 1024 + t;
  sd[t] = (i < NN) ? counts[i] : 0;
  __syncthreads();
  for (int off = 512; off > 0; off >>= 1) {
    if (t < off) sd[t] += sd[t + off];
    __syncthreads();
  }
  if (t == 0) bs[blockIdx.x] = sd[0];
}

// scan phase B: one wave scans the block sums -> exclusive offsets
__global__ void k_scanB(const int* __restrict__ bs, int* __restrict__ bo) {
  int lane = threadIdx.x & 63;
  int v = (lane < SCB) ? bs[lane] : 0;
  int orig = v;
  for (int off = 1; off < 64; off <<= 1) {
    int u = __shfl_up(v, off, 64);
    if (lane >= off) v += u;
  }
  if (lane < SCB) bo[lane] = v - orig;
}

// scan phase C: intra-block exclusive scan + offset -> row_ptr, cursor
__global__ __launch_bounds__(1024) void k_scanC(const int* __restrict__ counts,
                                                const int* __restrict__ bo,
                                                int* __restrict__ row_ptr,
                                                int* __restrict__ cursor) {
  __shared__ int sd[1024];
  int t = threadIdx.x;
  int i = blockIdx.x * 1024 + t;
  int v = (i < NN) ? counts[i] : 0;
  sd[t] = v;
  __syncthreads();
  for (int off = 1; off < 1024; off <<= 1) {
    int u = (t >= off) ? sd[t - off] : 0;
    __syncthreads();
    sd[t] += u;
    __syncthreads();
  }
  int excl = sd[t] - v + bo[blockIdx.x];
  if (i < NN) {
    row_ptr[i] = excl;
    cursor[i] = excl;
  }
  if (i == NN - 1) row_ptr[NN] = excl + v;
}

__global__ __launch_bounds__(256) void k_fill(const void* __restrict__ ei,
                                              const int* __restrict__ flags,
                                              int* __restrict__ cursor,
                                              int2* __restrict__ recs) {
  long long e = (long long)blockIdx.x * 256 + threadIdx.x;
  if (e >= NE) return;
  int i64 = flags[0];
  int src = ldidx(ei, e, i64);
  int dst = ldidx(ei, NE + e, i64);
  int pos = atomicAdd(&cursor[dst], 1);
  recs[pos] = make_int2(src, (int)e);
}

// ---------------- gather 1: per-group (8 lanes/node) pull; no cross-lane ops ----------------
__global__ __launch_bounds__(256) void k_gather1(
    const void* __restrict__ x, const void* __restrict__ ea,
    const int* __restrict__ row_ptr, const int2* __restrict__ recs,
    const int* __restrict__ flags, float* __restrict__ Sx, float* __restrict__ Se) {
  int lane = threadIdx.x & 63;
  int g = lane >> 3, c = lane & 7;
  int bf = flags[1];
  long long wid = ((long long)blockIdx.x * blockDim.x + threadIdx.x) >> 6;
  long long nw = ((long long)gridDim.x * blockDim.x) >> 6;
  for (long long b = wid; b < NB; b += nw) {
    int n = (int)(b * 8 + g);
    int beg = row_ptr[n];
    int deg = row_ptr[n + 1] - beg;
    float a0 = 0.f, a1 = 0.f, a2 = 0.f, a3 = 0.f, a4 = 0.f, a5 = 0.f, a6 = 0.f, a7 = 0.f;
    float e0 = 0.f, e1 = 0.f, e2 = 0.f, e3 = 0.f;
    if (bf) {
      const unsigned short* xs = (const unsigned short*)x;
      const unsigned short* es = (const unsigned short*)ea;
      for (int t = 0; __ballot(t < deg) != 0ull; ++t) {
        if (t < deg) {
          int2 r = recs[beg + t];
          uint4 w = *((const uint4*)(xs + ((long long)r.x << 6)) + c);
          a0 += bflo(w.x); a1 += bfhi(w.x);
          a2 += bflo(w.y); a3 += bfhi(w.y);
          a4 += bflo(w.z); a5 += bfhi(w.z);
          a6 += bflo(w.w); a7 += bfhi(w.w);
          if (c < 4) {
            uint2 q = *((const uint2*)(es + ((long long)r.y << 4)) + c);
            e0 += bflo(q.x); e1 += bfhi(q.x);
            e2 += bflo(q.y); e3 += bfhi(q.y);
          }
        }
      }
    } else {
      const float* xf = (const float*)x;
      const float* ef = (const float*)ea;
      for (int t = 0; __ballot(t < deg) != 0ull; ++t) {
        if (t < deg) {
          int2 r = recs[beg + t];
          float4 w0 = *((const float4*)(xf + ((long long)r.x << 6)) + c * 2);
          float4 w1 = *((const float4*)(xf + ((long long)r.x << 6)) + c * 2 + 1);
          a0 += w0.x; a1 += w0.y; a2 += w0.z; a3 += w0.w;
          a4 += w1.x; a5 += w1.y; a6 += w1.z; a7 += w1.w;
          if (c < 4) {
            float4 q = *((const float4*)(ef + ((long long)r.y << 4)) + c);
            e0 += q.x; e1 += q.y; e2 += q.z; e3 += q.w;
          }
        }
      }
    }
    float4* sxp = (float4*)(Sx + (long long)n * 64 + c * 8);
    sxp[0] = make_float4(a0, a1, a2, a3);
    sxp[1] = make_float4(a4, a5, a6, a7);
    if (c < 4) *(float4*)(Se + (long long)n * 16 + c * 4) = make_float4(e0, e1, e2, e3);
  }
}

// ---------------- gemm 1: batch-8 nodes/wave, LDS weights -> H, Y2 ----------------
__global__ __launch_bounds__(256) void k_gemm1(
    const void* __restrict__ x, const float* __restrict__ Sx,
    const float* __restrict__ Se, const int* __restrict__ row_ptr,
    const float* __restrict__ WT, const int* __restrict__ flags,
    float* __restrict__ H, float* __restrict__ Y2) {
  __shared__ float sw[11392];  // FW1X|FW1S|FW1E|FB1M|FB1S|FW2M (contiguous in WT)
  for (int i = threadIdx.x; i < 11392; i += 256) sw[i] = WT[i];
  __syncthreads();
  const float* swX = sw + W_FW1X;
  const float* swS = sw + W_FW1S;
  const float* swE = sw + W_FW1E;
  const float* swM = sw + W_FW2M;
  int lane = threadIdx.x & 63;
  int bf = flags[1];
  float fb1m = sw[W_FB1M + lane];
  float fb1s = sw[W_FB1S + lane];
  int j = lane & 31;
  long long wid = ((long long)blockIdx.x * blockDim.x + threadIdx.x) >> 6;
  long long nw = ((long long)gridDim.x * blockDim.x) >> 6;
  for (long long b = wid; b < NB; b += nw) {
    long long n0 = b * 8;
    float sxv[8], xv[8], sev[8], acc[8];
#pragma unroll
    for (int g = 0; g < 8; ++g) {
      long long n = n0 + g;
      sxv[g] = Sx[n * 64 + lane];
      xv[g] = ldf(x, n * 64 + lane, bf);
      sev[g] = Se[n * 16 + (lane & 15)];
      float dg = (float)(row_ptr[n + 1] - row_ptr[n]);
      acc[g] = fmaf(dg, fb1m, fb1s);
    }
#pragma unroll 4
    for (int k = 0; k < 64; ++k) {
      float wx = swX[k * 64 + lane];
      float wsf = swS[k * 64 + lane];
#pragma unroll
      for (int g = 0; g < 8; ++g) {
        acc[g] = fmaf(bcast(sxv[g], k), wx, acc[g]);
        acc[g] = fmaf(bcast(xv[g], k), wsf, acc[g]);
      }
    }
#pragma unroll 4
    for (int k = 0; k < 16; ++k) {
      float wel = swE[k * 64 + lane];
#pragma unroll
      for (int g = 0; g < 8; ++g) acc[g] = fmaf(bcast(sev[g], k), wel, acc[g]);
    }
#pragma unroll
    for (int g = 0; g < 8; ++g) {
      acc[g] = fmaxf(acc[g], 0.0f);
      H[(n0 + g) * 64 + lane] = acc[g];
    }
    // Y2 = H @ W2_msg[0:64,:]
    float y[8];
#pragma unroll
    for (int g = 0; g < 8; ++g) y[g] = 0.f;
#pragma unroll 4
    for (int k = 0; k < 64; ++k) {
      float wm = swM[k * 32 + j];
#pragma unroll
      for (int g = 0; g < 8; ++g) y[g] = fmaf(bcast(acc[g], k), wm, y[g]);
    }
    if (lane < 32) {
#pragma unroll
      for (int g = 0; g < 8; ++g) Y2[(n0 + g) * 32 + j] = y[g];
    }
  }
}

// ---------------- gather 2: per-group pull of Y2 rows -> S2 ----------------
__global__ __launch_bounds__(256) void k_gather2(
    const float* __restrict__ Y2, const int* __restrict__ row_ptr,
    const int2* __restrict__ recs, float* __restrict__ S2) {
  int lane = threadIdx.x & 63;
  int g = lane >> 3, c = lane & 7;
  long long wid = ((long long)blockIdx.x * blockDim.x + threadIdx.x) >> 6;
  long long nw = ((long long)gridDim.x * blockDim.x) >> 6;
  for (long long b = wid; b < NB; b += nw) {
    int n = (int)(b * 8 + g);
    int beg = row_ptr[n];
    int deg = row_ptr[n + 1] - beg;
    float s0 = 0.f, s1 = 0.f, s2 = 0.f, s3 = 0.f;
    for (int t = 0; __ballot(t < deg) != 0ull; ++t) {
      if (t < deg) {
        int2 r = recs[beg + t];
        float4 y = *((const float4*)(Y2 + (long long)r.x * 32) + c);
        s0 += y.x; s1 += y.y; s2 += y.z; s3 += y.w;
      }
    }
    *(float4*)(S2 + (long long)n * 32 + c * 4) = make_float4(s0, s1, s2, s3);
  }
}

// ---------------- gemm 2: batch-8 nodes/wave -> out ----------------
__global__ __launch_bounds__(256) void k_gemm2(
    const float* __restrict__ H, const float* __restrict__ Se,
    const float* __restrict__ S2, const int* __restrict__ row_ptr,
    const float* __restrict__ WT, const int* __restrict__ flags,
    void* __restrict__ out) {
  __shared__ float sw[2624];  // FW2E|FW2S|FB2M|FB2S (contiguous in WT at 11392)
  for (int i = threadIdx.x; i < 2624; i += 256) sw[i] = WT[11392 + i];
  __syncthreads();
  const float* swE = sw;        // 16x32
  const float* swS = sw + 512;  // 64x32
  int lane = threadIdx.x & 63;
  int bf = flags[1];
  int j = lane & 31;
  float fb2m = sw[2560 + j];
  float fb2s = sw[2592 + j];
  long long wid = ((long long)blockIdx.x * blockDim.x + threadIdx.x) >> 6;
  long long nw = ((long long)gridDim.x * blockDim.x) >> 6;
  for (long long b = wid; b < NB; b += nw) {
    long long n0 = b * 8;
    float hv[8], sev[8], acc[8];
#pragma unroll
    for (int g = 0; g < 8; ++g) {
      long long n = n0 + g;
      hv[g] = H[n * 64 + lane];
      sev[g] = Se[n * 16 + (lane & 15)];
      float dg = (float)(row_ptr[n + 1] - row_ptr[n]);
      acc[g] = fmaf(dg, fb2m, fb2s) + S2[n * 32 + j];
    }
#pragma unroll 4
    for (int k = 0; k < 64; ++k) {
      float w = swS[k * 32 + j];
#pragma unroll
      for (int g = 0; g < 8; ++g) acc[g] = fmaf(bcast(hv[g], k), w, acc[g]);
    }
#pragma unroll 4
    for (int k = 0; k < 16; ++k) {
      float w = swE[k * 32 + j];
#pragma unroll
      for (int g = 0; g < 8; ++g) acc[g] = fmaf(bcast(sev[g], k), w, acc[g]);
    }
    if (lane < 32) {
      if (bf) {
#pragma unroll
        for (int g = 0; g < 8; ++g)
          ((unsigned short*)out)[(n0 + g) * 32 + j] = f2bf(acc[g]);
      } else {
#pragma unroll
        for (int g = 0; g < 8; ++g) ((float*)out)[(n0 + g) * 32 + j] = acc[g];
      }
    }
  }
}

extern "C" void kernel_launch(void* const* d_in, const int* in_sizes, int n_in,
                              void* d_out, int out_size, void* d_ws, size_t ws_size,
                              hipStream_t stream) {
  const void* x = d_in[0];
  const void* ei = d_in[1];
  const void* ea = d_in[2];
  const void* W1_msg = d_in[3];
  const void* b1_msg = d_in[4];
  const void* W1_self = d_in[5];
  const void* b1_self = d_in[6];
  const void* gamma = d_in[7];
  const void* beta = d_in[8];
  const void* mean = d_in[9];
  const void* var = d_in[10];
  const void* W2_msg = d_in[11];
  const void* b2_msg = d_in[12];
  const void* W2_self = d_in[13];
  const void* b2_self = d_in[14];

  float* ws = (float*)d_ws;
  float* Se = ws + OFF_SE;
  float* H = ws + OFF_H;
  float* Y2 = ws + OFF_Y2;
  float* Sx = ws + OFF_SX;
  float* S2 = ws + OFF_SX;  // S2 reuses Sx space (Sx dead after k_gemm1)
  int* counts = (int*)(ws + OFF_CNT);
  int* row_ptr = (int*)(ws + OFF_ROW);
  int* cursor = (int*)(ws + OFF_CUR);
  int2* recs = (int2*)(ws + OFF_RECS);
  int* flags = (int*)(ws + OFF_FLAGS);
  int* bs = (int*)(ws + OFF_BS);
  int* bo = (int*)(ws + OFF_BO);
  float* WT = ws + OFF_WT;

  hipLaunchKernelGGL(k_detect, dim3(1), dim3(64), 0, stream, ei, x, flags);
  hipMemsetAsync(counts, 0, (size_t)NN * sizeof(int), stream);
  hipLaunchKernelGGL(k_prep, dim3(32), dim3(256), 0, stream, W1_msg, b1_msg, W1_self,
                     b1_self, gamma, beta, mean, var, W2_msg, b2_msg, W2_self, b2_self,
                     flags, WT);

  int eblocks = (NE + 255) / 256;
  hipLaunchKernelGGL(k_hist, dim3(eblocks), dim3(256), 0, stream, ei, flags, counts);
  hipLaunchKernelGGL(k_scanA, dim3(SCB), dim3(1024), 0, stream, counts, bs);
  hipLaunchKernelGGL(k_scanB, dim3(1), dim3(64), 0, stream, bs, bo);
  hipLaunchKernelGGL(k_scanC, dim3(SCB), dim3(1024), 0, stream, counts, bo, row_ptr,
                     cursor);
  hipLaunchKernelGGL(k_fill, dim3(eblocks), dim3(256), 0, stream, ei, flags, cursor, recs);

  int nblocks = (NB + 3) / 4;  // 4 waves/block
  hipLaunchKernelGGL(k_gather1, dim3(nblocks), dim3(256), 0, stream, x, ea, row_ptr,
                     recs, flags, Sx, Se);
  hipLaunchKernelGGL(k_gemm1, dim3(nblocks), dim3(256), 0, stream, x, Sx, Se, row_ptr,
                     WT, flags, H, Y2);
  hipLaunchKernelGGL(k_gather2, dim3(nblocks), dim3(256), 0, stream, Y2, row_ptr, recs,
                     S2);
  hipLaunchKernelGGL(k_gemm2, dim3(nblocks), dim3(256), 0, stream, H, Se, S2, row_ptr,
                     WT, flags, d_out);
}

// Round 8
// 301.845 us; speedup vs baseline: 2.7784x; 1.2462x over previous
//
#include <hip/hip_runtime.h>

#define NN 50000
#define NE 800000
#define NB 6250        // NN/8 gather batches
#define NT 3125        // NN/16 mfma tiles
#define SCB 49         // ceil(NN/1024) scan blocks

typedef __attribute__((ext_vector_type(8))) short short8x;
typedef __attribute__((ext_vector_type(4))) float f32x4;

// ws layout (float-index offsets)
#define OFF_CNT   0LL                 // NN ints
#define OFF_ROW   ((long long)NN)     // NN+1 ints
#define OFF_CUR   (2LL*NN + 8)        // NN ints
#define OFF_RECS  (3LL*NN + 16)       // NE int2 = 32NN ints
#define OFF_FLAGS (35LL*NN + 16)      // ints
#define OFF_BS    (35LL*NN + 32)      // 64 ints
#define OFF_BO    (35LL*NN + 96)      // 64 ints
#define OFF_PK    (35LL*NN + 160)     // 15360 ushorts = 7680 floats (16B-aligned base)
#define OFF_FB1S  (35LL*NN + 7840)    // 64 f32
#define OFF_FB2S  (35LL*NN + 7904)    // 32 f32
#define OFF_F1    (36LL*NN)           // NN*160 bf16
#define OFF_F2    (116LL*NN)          // NN*96 bf16
#define OFF_Y2B   (164LL*NN)          // NN*32 bf16
#define OFF_S2    (180LL*NN)          // NN*32 f32
// PK sublayout (ushort idx): B1 [0,10240) BY [10240,12288) B2 [12288,15360)

__device__ __forceinline__ float ldf(const void* p, long long i, int bf16) {
  if (bf16) {
    unsigned short u = ((const unsigned short*)p)[i];
    return __uint_as_float(((unsigned)u) << 16);
  }
  return ((const float*)p)[i];
}
__device__ __forceinline__ unsigned short f2bf(float f) {
  unsigned u = __float_as_uint(f);
  unsigned r = (u + 0x7fffu + ((u >> 16) & 1u)) >> 16;
  return (unsigned short)r;
}
__device__ __forceinline__ unsigned pk2(float lo, float hi) {
  return (unsigned)f2bf(lo) | ((unsigned)f2bf(hi) << 16);
}
__device__ __forceinline__ int ldidx(const void* p, long long i, int i64) {
  return i64 ? (int)((const long long*)p)[i] : ((const int*)p)[i];
}
__device__ __forceinline__ float bflo(unsigned u) { return __uint_as_float(u << 16); }
__device__ __forceinline__ float bfhi(unsigned u) { return __uint_as_float(u & 0xffff0000u); }

// ---------------- detect dtypes (wave-parallel) ----------------
__global__ void k_detect(const void* ei, const void* x, int* flags) {
  int lane = threadIdx.x & 63;
  const int* p = (const int*)ei;
  int any = 0;
  for (int i = lane; i < 256; i += 64) any |= p[2 * i + 1];
  unsigned long long anyb = __ballot(any != 0);
  const unsigned short* q = (const unsigned short*)x;
  int cnt = 0;
  for (int i = lane; i < 256; i += 64) {
    unsigned short w = q[2 * i];
    int e = (w >> 7) & 0xff;
    if (w == 0 || (e >= 110 && e <= 140)) cnt++;
  }
  for (int m = 1; m < 64; m <<= 1) cnt += __shfl_xor(cnt, m, 64);
  if (lane == 0) {
    flags[0] = (anyb == 0ull) ? 1 : 0;
    flags[1] = (cnt >= 192) ? 1 : 0;
  }
}

// ---------------- pack BN-folded weights into MFMA B-fragment order (bf16) ----------------
__global__ __launch_bounds__(256) void k_prep(
    const void* __restrict__ W1_msg, const void* __restrict__ b1_msg,
    const void* __restrict__ W1_self, const void* __restrict__ b1_self,
    const void* __restrict__ gamma, const void* __restrict__ beta,
    const void* __restrict__ mean, const void* __restrict__ var,
    const void* __restrict__ W2_msg, const void* __restrict__ b2_msg,
    const void* __restrict__ W2_self, const void* __restrict__ b2_self,
    const int* __restrict__ flags, unsigned short* __restrict__ PK,
    float* __restrict__ fb1s, float* __restrict__ fb2s) {
  int bf = flags[1];
  int t0 = blockIdx.x * 256 + threadIdx.x;
  int stride = gridDim.x * 256;
  // B1: F1 order [Sx(0..63)|x(64..127)|Se(128..143)|deg(144)|pad]
  for (int i = t0; i < 10240; i += stride) {
    int j = i & 7, L = (i >> 3) & 63, t = (i >> 9) & 3, c = i >> 11;
    int k = c * 32 + ((L >> 4) << 3) + j;
    int col = t * 16 + (L & 15);
    float sc = ldf(gamma, col, bf) * rsqrtf(ldf(var, col, bf) + 1e-5f);
    float v;
    if (k < 64) v = ldf(W1_msg, k * 64 + col, bf) * sc;
    else if (k < 128) v = ldf(W1_self, (k - 64) * 64 + col, bf) * sc;
    else if (k < 144) v = ldf(W1_msg, (64 + k - 128) * 64 + col, bf) * sc;
    else if (k == 144) v = ldf(b1_msg, col, bf) * sc;
    else v = 0.0f;
    PK[i] = f2bf(v);
  }
  // BY: W2_msg top 64 rows (K=64, 32 cols)
  for (int i = t0; i < 2048; i += stride) {
    int j = i & 7, L = (i >> 3) & 63, t = (i >> 9) & 1, c = i >> 10;
    int k = c * 32 + ((L >> 4) << 3) + j;
    int col = t * 16 + (L & 15);
    PK[10240 + i] = f2bf(ldf(W2_msg, k * 32 + col, bf));
  }
  // B2: F2 order [H(0..63)|Se(64..79)|deg(80)|pad]
  for (int i = t0; i < 3072; i += stride) {
    int j = i & 7, L = (i >> 3) & 63, t = (i >> 9) & 1, c = i >> 10;
    int k = c * 32 + ((L >> 4) << 3) + j;
    int col = t * 16 + (L & 15);
    float v;
    if (k < 64) v = ldf(W2_self, k * 32 + col, bf);
    else if (k < 80) v = ldf(W2_msg, k * 32 + col, bf);
    else if (k == 80) v = ldf(b2_msg, col, bf);
    else v = 0.0f;
    PK[12288 + i] = f2bf(v);
  }
  for (int i = t0; i < 64; i += stride) {
    float sc = ldf(gamma, i, bf) * rsqrtf(ldf(var, i, bf) + 1e-5f);
    fb1s[i] = ldf(b1_self, i, bf) * sc + ldf(beta, i, bf) - ldf(mean, i, bf) * sc;
  }
  for (int i = t0; i < 32; i += stride) fb2s[i] = ldf(b2_msg, i, bf) * 0.0f + ldf(b2_self, i, bf);
}

// ---------------- CSR build ----------------
__global__ __launch_bounds__(256) void k_hist(const void* __restrict__ ei,
                                              const int* __restrict__ flags,
                                              int* __restrict__ counts) {
  long long e = (long long)blockIdx.x * 256 + threadIdx.x;
  if (e >= NE) return;
  int dst = ldidx(ei, NE + e, flags[0]);
  atomicAdd(&counts[dst], 1);
}

__global__ __launch_bounds__(1024) void k_scanA(const int* __restrict__ counts,
                                                int* __restrict__ bs) {
  __shared__ int sd[1024];
  int t = threadIdx.x;
  int i = blockIdx.x * 1024 + t;
  sd[t] = (i < NN) ? counts[i] : 0;
  __syncthreads();
  for (int off = 512; off > 0; off >>= 1) {
    if (t < off) sd[t] += sd[t + off];
    __syncthreads();
  }
  if (t == 0) bs[blockIdx.x] = sd[0];
}

__global__ void k_scanB(const int* __restrict__ bs, int* __restrict__ bo) {
  int lane = threadIdx.x & 63;
  int v = (lane < SCB) ? bs[lane] : 0;
  int orig = v;
  for (int off = 1; off < 64; off <<= 1) {
    int u = __shfl_up(v, off, 64);
    if (lane >= off) v += u;
  }
  if (lane < SCB) bo[lane] = v - orig;
}

__global__ __launch_bounds__(1024) void k_scanC(const int* __restrict__ counts,
                                                const int* __restrict__ bo,
                                                int* __restrict__ row_ptr,
                                                int* __restrict__ cursor) {
  __shared__ int sd[1024];
  int t = threadIdx.x;
  int i = blockIdx.x * 1024 + t;
  int v = (i < NN) ? counts[i] : 0;
  sd[t] = v;
  __syncthreads();
  for (int off = 1; off < 1024; off <<= 1) {
    int u = (t >= off) ? sd[t - off] : 0;
    __syncthreads();
    sd[t] += u;
    __syncthreads();
  }
  int excl = sd[t] - v + bo[blockIdx.x];
  if (i < NN) {
    row_ptr[i] = excl;
    cursor[i] = excl;
  }
  if (i == NN - 1) row_ptr[NN] = excl + v;
}

__global__ __launch_bounds__(256) void k_fill(const void* __restrict__ ei,
                                              const int* __restrict__ flags,
                                              int* __restrict__ cursor,
                                              int2* __restrict__ recs) {
  long long e = (long long)blockIdx.x * 256 + threadIdx.x;
  if (e >= NE) return;
  int i64 = flags[0];
  int src = ldidx(ei, e, i64);
  int dst = ldidx(ei, NE + e, i64);
  int pos = atomicAdd(&cursor[dst], 1);
  recs[pos] = make_int2(src, (int)e);
}

// ---------------- gather 1: 8 lanes/node pull; writes packed bf16 F1 (+F2 tail) ----------------
__global__ __launch_bounds__(256) void k_gather1(
    const void* __restrict__ x, const void* __restrict__ ea,
    const int* __restrict__ row_ptr, const int2* __restrict__ recs,
    const int* __restrict__ flags, unsigned short* __restrict__ F1,
    unsigned short* __restrict__ F2) {
  int lane = threadIdx.x & 63;
  int g = lane >> 3, c = lane & 7;
  int bf = flags[1];
  long long wid = ((long long)blockIdx.x * blockDim.x + threadIdx.x) >> 6;
  long long nw = ((long long)gridDim.x * blockDim.x) >> 6;
  for (long long b = wid; b < NB; b += nw) {
    int n = (int)(b * 8 + g);
    int beg = row_ptr[n];
    int deg = row_ptr[n + 1] - beg;
    float a0 = 0.f, a1 = 0.f, a2 = 0.f, a3 = 0.f, a4 = 0.f, a5 = 0.f, a6 = 0.f, a7 = 0.f;
    float e0 = 0.f, e1 = 0.f, e2 = 0.f, e3 = 0.f;
    uint4 xw;
    if (bf) {
      const unsigned short* xs = (const unsigned short*)x;
      const unsigned short* es = (const unsigned short*)ea;
      for (int t = 0; __ballot(t < deg) != 0ull; ++t) {
        if (t < deg) {
          int2 r = recs[beg + t];
          uint4 w = *((const uint4*)(xs + ((long long)r.x << 6)) + c);
          a0 += bflo(w.x); a1 += bfhi(w.x);
          a2 += bflo(w.y); a3 += bfhi(w.y);
          a4 += bflo(w.z); a5 += bfhi(w.z);
          a6 += bflo(w.w); a7 += bfhi(w.w);
          if (c < 4) {
            uint2 q = *((const uint2*)(es + ((long long)r.y << 4)) + c);
            e0 += bflo(q.x); e1 += bfhi(q.x);
            e2 += bflo(q.y); e3 += bfhi(q.y);
          }
        }
      }
      xw = *((const uint4*)(xs + ((long long)n << 6)) + c);
    } else {
      const float* xf = (const float*)x;
      const float* ef = (const float*)ea;
      for (int t = 0; __ballot(t < deg) != 0ull; ++t) {
        if (t < deg) {
          int2 r = recs[beg + t];
          float4 w0 = *((const float4*)(xf + ((long long)r.x << 6)) + c * 2);
          float4 w1 = *((const float4*)(xf + ((long long)r.x << 6)) + c * 2 + 1);
          a0 += w0.x; a1 += w0.y; a2 += w0.z; a3 += w0.w;
          a4 += w1.x; a5 += w1.y; a6 += w1.z; a7 += w1.w;
          if (c < 4) {
            float4 q = *((const float4*)(ef + ((long long)r.y << 4)) + c);
            e0 += q.x; e1 += q.y; e2 += q.z; e3 += q.w;
          }
        }
      }
      float4 p0 = *((const float4*)(xf + ((long long)n << 6)) + c * 2);
      float4 p1 = *((const float4*)(xf + ((long long)n << 6)) + c * 2 + 1);
      xw = make_uint4(pk2(p0.x, p0.y), pk2(p0.z, p0.w), pk2(p1.x, p1.y), pk2(p1.z, p1.w));
    }
    unsigned short* f1 = F1 + (long long)n * 160;
    unsigned short* f2 = F2 + (long long)n * 96;
    *((uint4*)f1 + c) = make_uint4(pk2(a0, a1), pk2(a2, a3), pk2(a4, a5), pk2(a6, a7));
    *((uint4*)(f1 + 64) + c) = xw;
    if (c < 4) {
      uint2 sp = make_uint2(pk2(e0, e1), pk2(e2, e3));
      *((uint2*)(f1 + 128) + c) = sp;
      *((uint2*)(f2 + 64) + c) = sp;
    }
    if (c == 4) {
      unsigned d = (unsigned)f2bf((float)deg);
      *((uint4*)(f1 + 144)) = make_uint4(d, 0u, 0u, 0u);
      *((uint4*)(f2 + 80)) = make_uint4(d, 0u, 0u, 0u);
    }
    if (c == 5) {
      *((uint4*)(f1 + 152)) = make_uint4(0u, 0u, 0u, 0u);
      *((uint4*)(f2 + 88)) = make_uint4(0u, 0u, 0u, 0u);
    }
  }
}

// ---------------- gemm 1 (MFMA): F1@B1 + bias -> ReLU -> F2[0..64) (B from global) ----------------
__global__ __launch_bounds__(256) void k_gemm1(
    const unsigned short* __restrict__ F1, const unsigned short* __restrict__ PK,
    const float* __restrict__ fb1s, unsigned short* __restrict__ F2) {
  int lane = threadIdx.x & 63;
  int wv = threadIdx.x >> 6;
  int m = lane & 15, quad = lane >> 4;
  // hoist B fragments to registers (global PK is 16B-aligned by construction)
  short8x Bf[20];
#pragma unroll
  for (int s = 0; s < 20; ++s) Bf[s] = *(const short8x*)(PK + (s * 64 + lane) * 8);
  long long gw = (long long)blockIdx.x * 4 + wv;
  long long nw = (long long)gridDim.x * 4;
  for (long long tile = gw; tile < NT; tile += nw) {
    long long n0 = tile * 16;
    const unsigned short* f1 = F1 + (n0 + m) * 160 + quad * 8;
    short8x A[5];
#pragma unroll
    for (int cc = 0; cc < 5; ++cc) A[cc] = *(const short8x*)(f1 + cc * 32);
    f32x4 acc[4];
#pragma unroll
    for (int t = 0; t < 4; ++t) {
      float b = fb1s[t * 16 + m];
      acc[t] = (f32x4){b, b, b, b};
    }
#pragma unroll
    for (int cc = 0; cc < 5; ++cc) {
#pragma unroll
      for (int t = 0; t < 4; ++t)
        acc[t] = __builtin_amdgcn_mfma_f32_16x16x32_bf16(A[cc], Bf[cc * 4 + t], acc[t], 0, 0, 0);
    }
#pragma unroll
    for (int t = 0; t < 4; ++t) {
#pragma unroll
      for (int i = 0; i < 4; ++i) {
        float h = fmaxf(acc[t][i], 0.0f);
        F2[(n0 + quad * 4 + i) * 96 + t * 16 + m] = f2bf(h);
      }
    }
  }
}

// ---------------- gemm Y (MFMA): Y2 = F2[:,0:64] @ BY ----------------
__global__ __launch_bounds__(256) void k_gemmY(
    const unsigned short* __restrict__ F2, const unsigned short* __restrict__ PK,
    unsigned short* __restrict__ Y2B) {
  int lane = threadIdx.x & 63;
  int wv = threadIdx.x >> 6;
  int m = lane & 15, quad = lane >> 4;
  short8x Bf[4];
#pragma unroll
  for (int s = 0; s < 4; ++s) Bf[s] = *(const short8x*)(PK + 10240 + (s * 64 + lane) * 8);
  long long gw = (long long)blockIdx.x * 4 + wv;
  long long nw = (long long)gridDim.x * 4;
  for (long long tile = gw; tile < NT; tile += nw) {
    long long n0 = tile * 16;
    const unsigned short* f2 = F2 + (n0 + m) * 96 + quad * 8;
    f32x4 yacc[2];
    yacc[0] = (f32x4){0.f, 0.f, 0.f, 0.f};
    yacc[1] = (f32x4){0.f, 0.f, 0.f, 0.f};
#pragma unroll
    for (int cc = 0; cc < 2; ++cc) {
      short8x Ah = *(const short8x*)(f2 + cc * 32);
#pragma unroll
      for (int t = 0; t < 2; ++t)
        yacc[t] = __builtin_amdgcn_mfma_f32_16x16x32_bf16(Ah, Bf[cc * 2 + t], yacc[t], 0, 0, 0);
    }
#pragma unroll
    for (int t = 0; t < 2; ++t)
#pragma unroll
      for (int i = 0; i < 4; ++i)
        Y2B[(n0 + quad * 4 + i) * 32 + t * 16 + m] = f2bf(yacc[t][i]);
  }
}

// ---------------- gather 2: 8 lanes/node pull of bf16 Y2 rows -> S2 f32 ----------------
__global__ __launch_bounds__(256) void k_gather2(
    const unsigned short* __restrict__ Y2B, const int* __restrict__ row_ptr,
    const int2* __restrict__ recs, float* __restrict__ S2) {
  int lane = threadIdx.x & 63;
  int g = lane >> 3, c = lane & 7;
  long long wid = ((long long)blockIdx.x * blockDim.x + threadIdx.x) >> 6;
  long long nw = ((long long)gridDim.x * blockDim.x) >> 6;
  for (long long b = wid; b < NB; b += nw) {
    int n = (int)(b * 8 + g);
    int beg = row_ptr[n];
    int deg = row_ptr[n + 1] - beg;
    float s0 = 0.f, s1 = 0.f, s2 = 0.f, s3 = 0.f;
    for (int t = 0; __ballot(t < deg) != 0ull; ++t) {
      if (t < deg) {
        int2 r = recs[beg + t];
        uint2 q = *((const uint2*)(Y2B + (long long)r.x * 32) + c);
        s0 += bflo(q.x); s1 += bfhi(q.x);
        s2 += bflo(q.y); s3 += bfhi(q.y);
      }
    }
    *(float4*)(S2 + (long long)n * 32 + c * 4) = make_float4(s0, s1, s2, s3);
  }
}

// ---------------- gemm 2 (MFMA): F2@B2 + S2 + fb2s -> out (flag-typed stores) ----------------
__global__ __launch_bounds__(256) void k_gemm2(
    const unsigned short* __restrict__ F2, const unsigned short* __restrict__ PK,
    const float* __restrict__ fb2s, const float* __restrict__ S2,
    const int* __restrict__ flags, void* __restrict__ out) {
  int lane = threadIdx.x & 63;
  int wv = threadIdx.x >> 6;
  int m = lane & 15, quad = lane >> 4;
  int bf = flags[1];
  short8x Bf[6];
#pragma unroll
  for (int s = 0; s < 6; ++s) Bf[s] = *(const short8x*)(PK + 12288 + (s * 64 + lane) * 8);
  long long gw = (long long)blockIdx.x * 4 + wv;
  long long nw = (long long)gridDim.x * 4;
  for (long long tile = gw; tile < NT; tile += nw) {
    long long n0 = tile * 16;
    const unsigned short* f2 = F2 + (n0 + m) * 96 + quad * 8;
    short8x A[3];
#pragma unroll
    for (int cc = 0; cc < 3; ++cc) A[cc] = *(const short8x*)(f2 + cc * 32);
    f32x4 acc[2];
#pragma unroll
    for (int t = 0; t < 2; ++t) {
      float b = fb2s[t * 16 + m];
#pragma unroll
      for (int i = 0; i < 4; ++i)
        acc[t][i] = b + S2[(n0 + quad * 4 + i) * 32 + t * 16 + m];
    }
#pragma unroll
    for (int cc = 0; cc < 3; ++cc) {
#pragma unroll
      for (int t = 0; t < 2; ++t)
        acc[t] = __builtin_amdgcn_mfma_f32_16x16x32_bf16(A[cc], Bf[cc * 2 + t], acc[t], 0, 0, 0);
    }
#pragma unroll
    for (int t = 0; t < 2; ++t) {
#pragma unroll
      for (int i = 0; i < 4; ++i) {
        long long idx = (n0 + quad * 4 + i) * 32 + t * 16 + m;
        if (bf) ((unsigned short*)out)[idx] = f2bf(acc[t][i]);
        else ((float*)out)[idx] = acc[t][i];
      }
    }
  }
}

extern "C" void kernel_launch(void* const* d_in, const int* in_sizes, int n_in,
                              void* d_out, int out_size, void* d_ws, size_t ws_size,
                              hipStream_t stream) {
  const void* x = d_in[0];
  const void* ei = d_in[1];
  const void* ea = d_in[2];
  const void* W1_msg = d_in[3];
  const void* b1_msg = d_in[4];
  const void* W1_self = d_in[5];
  const void* b1_self = d_in[6];
  const void* gamma = d_in[7];
  const void* beta = d_in[8];
  const void* mean = d_in[9];
  const void* var = d_in[10];
  const void* W2_msg = d_in[11];
  const void* b2_msg = d_in[12];
  const void* W2_self = d_in[13];
  const void* b2_self = d_in[14];

  float* ws = (float*)d_ws;
  int* counts = (int*)(ws + OFF_CNT);
  int* row_ptr = (int*)(ws + OFF_ROW);
  int* cursor = (int*)(ws + OFF_CUR);
  int2* recs = (int2*)(ws + OFF_RECS);
  int* flags = (int*)(ws + OFF_FLAGS);
  int* bs = (int*)(ws + OFF_BS);
  int* bo = (int*)(ws + OFF_BO);
  unsigned short* PK = (unsigned short*)(ws + OFF_PK);
  float* fb1s = ws + OFF_FB1S;
  float* fb2s = ws + OFF_FB2S;
  unsigned short* F1 = (unsigned short*)(ws + OFF_F1);
  unsigned short* F2 = (unsigned short*)(ws + OFF_F2);
  unsigned short* Y2B = (unsigned short*)(ws + OFF_Y2B);
  float* S2 = ws + OFF_S2;

  hipLaunchKernelGGL(k_detect, dim3(1), dim3(64), 0, stream, ei, x, flags);
  hipMemsetAsync(counts, 0, (size_t)NN * sizeof(int), stream);
  hipLaunchKernelGGL(k_prep, dim3(64), dim3(256), 0, stream, W1_msg, b1_msg, W1_self,
                     b1_self, gamma, beta, mean, var, W2_msg, b2_msg, W2_self, b2_self,
                     flags, PK, fb1s, fb2s);

  int eblocks = (NE + 255) / 256;
  hipLaunchKernelGGL(k_hist, dim3(eblocks), dim3(256), 0, stream, ei, flags, counts);
  hipLaunchKernelGGL(k_scanA, dim3(SCB), dim3(1024), 0, stream, counts, bs);
  hipLaunchKernelGGL(k_scanB, dim3(1), dim3(64), 0, stream, bs, bo);
  hipLaunchKernelGGL(k_scanC, dim3(SCB), dim3(1024), 0, stream, counts, bo, row_ptr,
                     cursor);
  hipLaunchKernelGGL(k_fill, dim3(eblocks), dim3(256), 0, stream, ei, flags, cursor, recs);

  int gblocks = (NB + 3) / 4;
  hipLaunchKernelGGL(k_gather1, dim3(gblocks), dim3(256), 0, stream, x, ea, row_ptr,
                     recs, flags, F1, F2);
  int mblocks = (NT + 3) / 4;
  hipLaunchKernelGGL(k_gemm1, dim3(mblocks), dim3(256), 0, stream, F1, PK, fb1s, F2);
  hipLaunchKernelGGL(k_gemmY, dim3(mblocks), dim3(256), 0, stream, F2, PK, Y2B);
  hipLaunchKernelGGL(k_gather2, dim3(gblocks), dim3(256), 0, stream, Y2B, row_ptr, recs,
                     S2);
  hipLaunchKernelGGL(k_gemm2, dim3(mblocks), dim3(256), 0, stream, F2, PK, fb2s, S2,
                     flags, d_out);
}

// Round 9
// 249.097 us; speedup vs baseline: 3.3667x; 1.2118x over previous
//
#include <hip/hip_runtime.h>

#define NN 50000
#define NE 800000
#define NB 6250        // NN/8 gather batches
#define NT 3125        // NN/16 mfma tiles
#define SCB 49         // ceil(NN/1024) scan blocks
#define NBK 128        // coarse buckets
#define BNODE 391      // nodes per bucket (391*128 = 50048 >= NN)
#define BCAP 7680      // bucket capacity (mean 6250, +18 sigma)
#define SCAP 56        // per-block LDS stage capacity per bucket

typedef __attribute__((ext_vector_type(8))) short short8x;
typedef __attribute__((ext_vector_type(4))) float f32x4;

// ws layout (float-index offsets)
#define OFF_CNT   0LL                 // NN ints (counts)
#define OFF_ROW   ((long long)NN)     // NN+1 ints (row_ptr)
#define OFF_RECS  (3LL*NN + 16)       // NE int2
#define OFF_FLAGS (35LL*NN + 16)      // ints
#define OFF_BS    (35LL*NN + 32)      // 64 ints
#define OFF_BO    (35LL*NN + 96)      // 64 ints
#define OFF_PK    (35LL*NN + 160)     // 15360 ushorts (16B-aligned)
#define OFF_FB1S  (35LL*NN + 7840)    // 64 f32
#define OFF_FB2S  (35LL*NN + 7904)    // 32 f32
#define OFF_F1    (36LL*NN)           // NN*160 bf16  (binbuf aliases this region)
#define OFF_F2    (116LL*NN)          // NN*96 bf16
#define OFF_Y2B   (164LL*NN)          // NN*32 bf16
#define OFF_S2    (180LL*NN)          // NN*32 f32
#define OFF_BCUR  (212LL*NN)          // 128 ints

__device__ __forceinline__ float ldf(const void* p, long long i, int bf16) {
  if (bf16) {
    unsigned short u = ((const unsigned short*)p)[i];
    return __uint_as_float(((unsigned)u) << 16);
  }
  return ((const float*)p)[i];
}
__device__ __forceinline__ unsigned short f2bf(float f) {
  unsigned u = __float_as_uint(f);
  unsigned r = (u + 0x7fffu + ((u >> 16) & 1u)) >> 16;
  return (unsigned short)r;
}
__device__ __forceinline__ unsigned pk2(float lo, float hi) {
  return (unsigned)f2bf(lo) | ((unsigned)f2bf(hi) << 16);
}
__device__ __forceinline__ int ldidx(const void* p, long long i, int i64) {
  return i64 ? (int)((const long long*)p)[i] : ((const int*)p)[i];
}
__device__ __forceinline__ float bflo(unsigned u) { return __uint_as_float(u << 16); }
__device__ __forceinline__ float bfhi(unsigned u) { return __uint_as_float(u & 0xffff0000u); }

// ---------------- detect dtypes ----------------
__global__ void k_detect(const void* ei, const void* x, int* flags) {
  int lane = threadIdx.x & 63;
  const int* p = (const int*)ei;
  int any = 0;
  for (int i = lane; i < 256; i += 64) any |= p[2 * i + 1];
  unsigned long long anyb = __ballot(any != 0);
  const unsigned short* q = (const unsigned short*)x;
  int cnt = 0;
  for (int i = lane; i < 256; i += 64) {
    unsigned short w = q[2 * i];
    int e = (w >> 7) & 0xff;
    if (w == 0 || (e >= 110 && e <= 140)) cnt++;
  }
  for (int m = 1; m < 64; m <<= 1) cnt += __shfl_xor(cnt, m, 64);
  if (lane == 0) {
    flags[0] = (anyb == 0ull) ? 1 : 0;
    flags[1] = (cnt >= 192) ? 1 : 0;
  }
}

// ---------------- pack BN-folded weights into MFMA B-fragment order ----------------
__global__ __launch_bounds__(256) void k_prep(
    const void* __restrict__ W1_msg, const void* __restrict__ b1_msg,
    const void* __restrict__ W1_self, const void* __restrict__ b1_self,
    const void* __restrict__ gamma, const void* __restrict__ beta,
    const void* __restrict__ mean, const void* __restrict__ var,
    const void* __restrict__ W2_msg, const void* __restrict__ b2_msg,
    const void* __restrict__ W2_self, const void* __restrict__ b2_self,
    const int* __restrict__ flags, unsigned short* __restrict__ PK,
    float* __restrict__ fb1s, float* __restrict__ fb2s) {
  int bf = flags[1];
  int t0 = blockIdx.x * 256 + threadIdx.x;
  int stride = gridDim.x * 256;
  for (int i = t0; i < 10240; i += stride) {
    int j = i & 7, L = (i >> 3) & 63, t = (i >> 9) & 3, c = i >> 11;
    int k = c * 32 + ((L >> 4) << 3) + j;
    int col = t * 16 + (L & 15);
    float sc = ldf(gamma, col, bf) * rsqrtf(ldf(var, col, bf) + 1e-5f);
    float v;
    if (k < 64) v = ldf(W1_msg, k * 64 + col, bf) * sc;
    else if (k < 128) v = ldf(W1_self, (k - 64) * 64 + col, bf) * sc;
    else if (k < 144) v = ldf(W1_msg, (64 + k - 128) * 64 + col, bf) * sc;
    else if (k == 144) v = ldf(b1_msg, col, bf) * sc;
    else v = 0.0f;
    PK[i] = f2bf(v);
  }
  for (int i = t0; i < 2048; i += stride) {
    int j = i & 7, L = (i >> 3) & 63, t = (i >> 9) & 1, c = i >> 10;
    int k = c * 32 + ((L >> 4) << 3) + j;
    int col = t * 16 + (L & 15);
    PK[10240 + i] = f2bf(ldf(W2_msg, k * 32 + col, bf));
  }
  for (int i = t0; i < 3072; i += stride) {
    int j = i & 7, L = (i >> 3) & 63, t = (i >> 9) & 1, c = i >> 10;
    int k = c * 32 + ((L >> 4) << 3) + j;
    int col = t * 16 + (L & 15);
    float v;
    if (k < 64) v = ldf(W2_self, k * 32 + col, bf);
    else if (k < 80) v = ldf(W2_msg, k * 32 + col, bf);
    else if (k == 80) v = ldf(b2_msg, col, bf);
    else v = 0.0f;
    PK[12288 + i] = f2bf(v);
  }
  for (int i = t0; i < 64; i += stride) {
    float sc = ldf(gamma, i, bf) * rsqrtf(ldf(var, i, bf) + 1e-5f);
    fb1s[i] = ldf(b1_self, i, bf) * sc + ldf(beta, i, bf) - ldf(mean, i, bf) * sc;
  }
  for (int i = t0; i < 32; i += stride) fb2s[i] = ldf(b2_self, i, bf);
}

// ---------------- phase 1: LDS-staged binning by dst/391 ----------------
__global__ __launch_bounds__(256) void k_bin(const void* __restrict__ ei,
                                             const int* __restrict__ flags,
                                             int* __restrict__ bcur,
                                             int2* __restrict__ binbuf) {
  __shared__ int2 stage[NBK][SCAP];  // 57.3 KB
  __shared__ int scnt[NBK];
  __shared__ int gbase[NBK];
  int tid = threadIdx.x;
  for (int i = tid; i < NBK; i += 256) scnt[i] = 0;
  __syncthreads();
  int i64 = flags[0];
  for (long long e0 = (long long)blockIdx.x * 256; e0 < NE;
       e0 += (long long)gridDim.x * 256) {
    long long e = e0 + tid;
    if (e < NE) {
      int src = ldidx(ei, e, i64);
      int dst = ldidx(ei, NE + e, i64);
      int b = dst / BNODE;
      int dl = dst - b * BNODE;
      int2 ent = make_int2(src | (dl << 16), (int)e);
      int pos = atomicAdd(&scnt[b], 1);
      if (pos < SCAP) {
        stage[b][pos] = ent;
      } else {  // rare overflow: direct global placement
        int gp = atomicAdd(&bcur[b], 1);
        binbuf[(long long)b * BCAP + gp] = ent;
      }
    }
  }
  __syncthreads();
  if (tid < NBK) {
    int cb = scnt[tid] < SCAP ? scnt[tid] : SCAP;
    gbase[tid] = atomicAdd(&bcur[tid], cb);
  }
  __syncthreads();
  for (int b = 0; b < NBK; ++b) {
    int cb = scnt[b] < SCAP ? scnt[b] : SCAP;
    for (int i = tid; i < cb; i += 256)
      binbuf[(long long)b * BCAP + gbase[b] + i] = stage[b][i];
  }
}

// ---------------- phase 1.5: per-bucket LDS histogram -> counts ----------------
__global__ __launch_bounds__(256) void k_bhist(const int* __restrict__ bcur,
                                               const int2* __restrict__ binbuf,
                                               int* __restrict__ counts) {
  __shared__ int lh[BNODE];
  int b = blockIdx.x;
  int tid = threadIdx.x;
  for (int i = tid; i < BNODE; i += 256) lh[i] = 0;
  __syncthreads();
  int cnt = bcur[b];
  for (int i = tid; i < cnt; i += 256) {
    int dl = (binbuf[(long long)b * BCAP + i].x >> 16) & 0x3FF;
    atomicAdd(&lh[dl], 1);
  }
  __syncthreads();
  int base = b * BNODE;
  int nn = NN - base < BNODE ? NN - base : BNODE;
  for (int i = tid; i < nn; i += 256) counts[base + i] = lh[i];
}

// ---------------- scan (3 phases) ----------------
__global__ __launch_bounds__(1024) void k_scanA(const int* __restrict__ counts,
                                                int* __restrict__ bs) {
  __shared__ int sd[1024];
  int t = threadIdx.x;
  int i = blockIdx.x * 1024 + t;
  sd[t] = (i < NN) ? counts[i] : 0;
  __syncthreads();
  for (int off = 512; off > 0; off >>= 1) {
    if (t < off) sd[t] += sd[t + off];
    __syncthreads();
  }
  if (t == 0) bs[blockIdx.x] = sd[0];
}

__global__ void k_scanB(const int* __restrict__ bs, int* __restrict__ bo) {
  int lane = threadIdx.x & 63;
  int v = (lane < SCB) ? bs[lane] : 0;
  int orig = v;
  for (int off = 1; off < 64; off <<= 1) {
    int u = __shfl_up(v, off, 64);
    if (lane >= off) v += u;
  }
  if (lane < SCB) bo[lane] = v - orig;
}

__global__ __launch_bounds__(1024) void k_scanC(const int* __restrict__ counts,
                                                const int* __restrict__ bo,
                                                int* __restrict__ row_ptr) {
  __shared__ int sd[1024];
  int t = threadIdx.x;
  int i = blockIdx.x * 1024 + t;
  int v = (i < NN) ? counts[i] : 0;
  sd[t] = v;
  __syncthreads();
  for (int off = 1; off < 1024; off <<= 1) {
    int u = (t >= off) ? sd[t - off] : 0;
    __syncthreads();
    sd[t] += u;
    __syncthreads();
  }
  int excl = sd[t] - v + bo[blockIdx.x];
  if (i < NN) row_ptr[i] = excl;
  if (i == NN - 1) row_ptr[NN] = excl + v;
}

// ---------------- phase 2: per-bucket LDS placement -> recs (coalesced) ----------------
__global__ __launch_bounds__(256) void k_place(const int* __restrict__ bcur,
                                               const int2* __restrict__ binbuf,
                                               const int* __restrict__ row_ptr,
                                               int2* __restrict__ recs) {
  __shared__ int2 outb[BCAP];  // 60 KB
  __shared__ int lcur[BNODE];
  int b = blockIdx.x;
  int tid = threadIdx.x;
  int base = b * BNODE;
  int nn = NN - base < BNODE ? NN - base : BNODE;
  int rbase = row_ptr[base];
  for (int i = tid; i < nn; i += 256) lcur[i] = row_ptr[base + i] - rbase;
  __syncthreads();
  int cnt = bcur[b];
  for (int i = tid; i < cnt; i += 256) {
    int2 ent = binbuf[(long long)b * BCAP + i];
    int dl = (ent.x >> 16) & 0x3FF;
    int p = atomicAdd(&lcur[dl], 1);
    outb[p] = make_int2(ent.x & 0xFFFF, ent.y);
  }
  __syncthreads();
  for (int i = tid; i < cnt; i += 256) recs[rbase + i] = outb[i];
}

// ---------------- gather 1: 8 lanes/node, unroll-4 -> packed bf16 F1 (+F2 tail) ----------------
__global__ __launch_bounds__(256) void k_gather1(
    const void* __restrict__ x, const void* __restrict__ ea,
    const int* __restrict__ row_ptr, const int2* __restrict__ recs,
    const int* __restrict__ flags, unsigned short* __restrict__ F1,
    unsigned short* __restrict__ F2) {
  int lane = threadIdx.x & 63;
  int g = lane >> 3, c = lane & 7;
  int bf = flags[1];
  long long wid = ((long long)blockIdx.x * blockDim.x + threadIdx.x) >> 6;
  long long nw = ((long long)gridDim.x * blockDim.x) >> 6;
  for (long long b = wid; b < NB; b += nw) {
    int n = (int)(b * 8 + g);
    int beg = row_ptr[n];
    int deg = row_ptr[n + 1] - beg;
    float a0 = 0.f, a1 = 0.f, a2 = 0.f, a3 = 0.f, a4 = 0.f, a5 = 0.f, a6 = 0.f, a7 = 0.f;
    float e0 = 0.f, e1 = 0.f, e2 = 0.f, e3 = 0.f;
    uint4 xw;
    if (bf) {
      const unsigned short* xs = (const unsigned short*)x;
      const unsigned short* es = (const unsigned short*)ea;
      int t = 0;
      for (; t + 4 <= deg; t += 4) {
        int2 r0 = recs[beg + t + 0];
        int2 r1 = recs[beg + t + 1];
        int2 r2 = recs[beg + t + 2];
        int2 r3 = recs[beg + t + 3];
        uint4 w0 = *((const uint4*)(xs + ((long long)r0.x << 6)) + c);
        uint4 w1 = *((const uint4*)(xs + ((long long)r1.x << 6)) + c);
        uint4 w2 = *((const uint4*)(xs + ((long long)r2.x << 6)) + c);
        uint4 w3 = *((const uint4*)(xs + ((long long)r3.x << 6)) + c);
        a0 += bflo(w0.x) + bflo(w1.x) + bflo(w2.x) + bflo(w3.x);
        a1 += bfhi(w0.x) + bfhi(w1.x) + bfhi(w2.x) + bfhi(w3.x);
        a2 += bflo(w0.y) + bflo(w1.y) + bflo(w2.y) + bflo(w3.y);
        a3 += bfhi(w0.y) + bfhi(w1.y) + bfhi(w2.y) + bfhi(w3.y);
        a4 += bflo(w0.z) + bflo(w1.z) + bflo(w2.z) + bflo(w3.z);
        a5 += bfhi(w0.z) + bfhi(w1.z) + bfhi(w2.z) + bfhi(w3.z);
        a6 += bflo(w0.w) + bflo(w1.w) + bflo(w2.w) + bflo(w3.w);
        a7 += bfhi(w0.w) + bfhi(w1.w) + bfhi(w2.w) + bfhi(w3.w);
        if (c < 4) {
          uint2 q0 = *((const uint2*)(es + ((long long)r0.y << 4)) + c);
          uint2 q1 = *((const uint2*)(es + ((long long)r1.y << 4)) + c);
          uint2 q2 = *((const uint2*)(es + ((long long)r2.y << 4)) + c);
          uint2 q3 = *((const uint2*)(es + ((long long)r3.y << 4)) + c);
          e0 += bflo(q0.x) + bflo(q1.x) + bflo(q2.x) + bflo(q3.x);
          e1 += bfhi(q0.x) + bfhi(q1.x) + bfhi(q2.x) + bfhi(q3.x);
          e2 += bflo(q0.y) + bflo(q1.y) + bflo(q2.y) + bflo(q3.y);
          e3 += bfhi(q0.y) + bfhi(q1.y) + bfhi(q2.y) + bfhi(q3.y);
        }
      }
      for (; t < deg; ++t) {
        int2 r = recs[beg + t];
        uint4 w = *((const uint4*)(xs + ((long long)r.x << 6)) + c);
        a0 += bflo(w.x); a1 += bfhi(w.x);
        a2 += bflo(w.y); a3 += bfhi(w.y);
        a4 += bflo(w.z); a5 += bfhi(w.z);
        a6 += bflo(w.w); a7 += bfhi(w.w);
        if (c < 4) {
          uint2 q = *((const uint2*)(es + ((long long)r.y << 4)) + c);
          e0 += bflo(q.x); e1 += bfhi(q.x);
          e2 += bflo(q.y); e3 += bfhi(q.y);
        }
      }
      xw = *((const uint4*)(xs + ((long long)n << 6)) + c);
    } else {
      const float* xf = (const float*)x;
      const float* ef = (const float*)ea;
      for (int t = 0; t < deg; ++t) {
        int2 r = recs[beg + t];
        float4 w0 = *((const float4*)(xf + ((long long)r.x << 6)) + c * 2);
        float4 w1 = *((const float4*)(xf + ((long long)r.x << 6)) + c * 2 + 1);
        a0 += w0.x; a1 += w0.y; a2 += w0.z; a3 += w0.w;
        a4 += w1.x; a5 += w1.y; a6 += w1.z; a7 += w1.w;
        if (c < 4) {
          float4 q = *((const float4*)(ef + ((long long)r.y << 4)) + c);
          e0 += q.x; e1 += q.y; e2 += q.z; e3 += q.w;
        }
      }
      float4 p0 = *((const float4*)(xf + ((long long)n << 6)) + c * 2);
      float4 p1 = *((const float4*)(xf + ((long long)n << 6)) + c * 2 + 1);
      xw = make_uint4(pk2(p0.x, p0.y), pk2(p0.z, p0.w), pk2(p1.x, p1.y), pk2(p1.z, p1.w));
    }
    unsigned short* f1 = F1 + (long long)n * 160;
    unsigned short* f2 = F2 + (long long)n * 96;
    *((uint4*)f1 + c) = make_uint4(pk2(a0, a1), pk2(a2, a3), pk2(a4, a5), pk2(a6, a7));
    *((uint4*)(f1 + 64) + c) = xw;
    if (c < 4) {
      uint2 sp = make_uint2(pk2(e0, e1), pk2(e2, e3));
      *((uint2*)(f1 + 128) + c) = sp;
      *((uint2*)(f2 + 64) + c) = sp;
    }
    if (c == 4) {
      unsigned d = (unsigned)f2bf((float)deg);
      *((uint4*)(f1 + 144)) = make_uint4(d, 0u, 0u, 0u);
      *((uint4*)(f2 + 80)) = make_uint4(d, 0u, 0u, 0u);
    }
    if (c == 5) {
      *((uint4*)(f1 + 152)) = make_uint4(0u, 0u, 0u, 0u);
      *((uint4*)(f2 + 88)) = make_uint4(0u, 0u, 0u, 0u);
    }
  }
}

// ---------------- gemm 1 (MFMA): F1@B1 + bias -> ReLU -> F2[0..64) ----------------
__global__ __launch_bounds__(256) void k_gemm1(
    const unsigned short* __restrict__ F1, const unsigned short* __restrict__ PK,
    const float* __restrict__ fb1s, unsigned short* __restrict__ F2) {
  int lane = threadIdx.x & 63;
  int wv = threadIdx.x >> 6;
  int m = lane & 15, quad = lane >> 4;
  short8x Bf[20];
#pragma unroll
  for (int s = 0; s < 20; ++s) Bf[s] = *(const short8x*)(PK + (s * 64 + lane) * 8);
  long long gw = (long long)blockIdx.x * 4 + wv;
  long long nw = (long long)gridDim.x * 4;
  for (long long tile = gw; tile < NT; tile += nw) {
    long long n0 = tile * 16;
    const unsigned short* f1 = F1 + (n0 + m) * 160 + quad * 8;
    short8x A[5];
#pragma unroll
    for (int cc = 0; cc < 5; ++cc) A[cc] = *(const short8x*)(f1 + cc * 32);
    f32x4 acc[4];
#pragma unroll
    for (int t = 0; t < 4; ++t) {
      float b = fb1s[t * 16 + m];
      acc[t] = (f32x4){b, b, b, b};
    }
#pragma unroll
    for (int cc = 0; cc < 5; ++cc) {
#pragma unroll
      for (int t = 0; t < 4; ++t)
        acc[t] = __builtin_amdgcn_mfma_f32_16x16x32_bf16(A[cc], Bf[cc * 4 + t], acc[t], 0, 0, 0);
    }
#pragma unroll
    for (int t = 0; t < 4; ++t) {
#pragma unroll
      for (int i = 0; i < 4; ++i) {
        float h = fmaxf(acc[t][i], 0.0f);
        F2[(n0 + quad * 4 + i) * 96 + t * 16 + m] = f2bf(h);
      }
    }
  }
}

// ---------------- gemm Y (MFMA): Y2 = F2[:,0:64] @ BY ----------------
__global__ __launch_bounds__(256) void k_gemmY(
    const unsigned short* __restrict__ F2, const unsigned short* __restrict__ PK,
    unsigned short* __restrict__ Y2B) {
  int lane = threadIdx.x & 63;
  int wv = threadIdx.x >> 6;
  int m = lane & 15, quad = lane >> 4;
  short8x Bf[4];
#pragma unroll
  for (int s = 0; s < 4; ++s) Bf[s] = *(const short8x*)(PK + 10240 + (s * 64 + lane) * 8);
  long long gw = (long long)blockIdx.x * 4 + wv;
  long long nw = (long long)gridDim.x * 4;
  for (long long tile = gw; tile < NT; tile += nw) {
    long long n0 = tile * 16;
    const unsigned short* f2 = F2 + (n0 + m) * 96 + quad * 8;
    f32x4 yacc[2];
    yacc[0] = (f32x4){0.f, 0.f, 0.f, 0.f};
    yacc[1] = (f32x4){0.f, 0.f, 0.f, 0.f};
#pragma unroll
    for (int cc = 0; cc < 2; ++cc) {
      short8x Ah = *(const short8x*)(f2 + cc * 32);
#pragma unroll
      for (int t = 0; t < 2; ++t)
        yacc[t] = __builtin_amdgcn_mfma_f32_16x16x32_bf16(Ah, Bf[cc * 2 + t], yacc[t], 0, 0, 0);
    }
#pragma unroll
    for (int t = 0; t < 2; ++t)
#pragma unroll
      for (int i = 0; i < 4; ++i)
        Y2B[(n0 + quad * 4 + i) * 32 + t * 16 + m] = f2bf(yacc[t][i]);
  }
}

// ---------------- gather 2: 8 lanes/node, unroll-4, bf16 Y2 rows -> S2 f32 ----------------
__global__ __launch_bounds__(256) void k_gather2(
    const unsigned short* __restrict__ Y2B, const int* __restrict__ row_ptr,
    const int2* __restrict__ recs, float* __restrict__ S2) {
  int lane = threadIdx.x & 63;
  int g = lane >> 3, c = lane & 7;
  long long wid = ((long long)blockIdx.x * blockDim.x + threadIdx.x) >> 6;
  long long nw = ((long long)gridDim.x * blockDim.x) >> 6;
  for (long long b = wid; b < NB; b += nw) {
    int n = (int)(b * 8 + g);
    int beg = row_ptr[n];
    int deg = row_ptr[n + 1] - beg;
    float s0 = 0.f, s1 = 0.f, s2 = 0.f, s3 = 0.f;
    int t = 0;
    for (; t + 4 <= deg; t += 4) {
      int2 r0 = recs[beg + t + 0];
      int2 r1 = recs[beg + t + 1];
      int2 r2 = recs[beg + t + 2];
      int2 r3 = recs[beg + t + 3];
      uint2 q0 = *((const uint2*)(Y2B + (long long)r0.x * 32) + c);
      uint2 q1 = *((const uint2*)(Y2B + (long long)r1.x * 32) + c);
      uint2 q2 = *((const uint2*)(Y2B + (long long)r2.x * 32) + c);
      uint2 q3 = *((const uint2*)(Y2B + (long long)r3.x * 32) + c);
      s0 += bflo(q0.x) + bflo(q1.x) + bflo(q2.x) + bflo(q3.x);
      s1 += bfhi(q0.x) + bfhi(q1.x) + bfhi(q2.x) + bfhi(q3.x);
      s2 += bflo(q0.y) + bflo(q1.y) + bflo(q2.y) + bflo(q3.y);
      s3 += bfhi(q0.y) + bfhi(q1.y) + bfhi(q2.y) + bfhi(q3.y);
    }
    for (; t < deg; ++t) {
      int2 r = recs[beg + t];
      uint2 q = *((const uint2*)(Y2B + (long long)r.x * 32) + c);
      s0 += bflo(q.x); s1 += bfhi(q.x);
      s2 += bflo(q.y); s3 += bfhi(q.y);
    }
    *(float4*)(S2 + (long long)n * 32 + c * 4) = make_float4(s0, s1, s2, s3);
  }
}

// ---------------- gemm 2 (MFMA): F2@B2 + S2 + fb2s -> out ----------------
__global__ __launch_bounds__(256) void k_gemm2(
    const unsigned short* __restrict__ F2, const unsigned short* __restrict__ PK,
    const float* __restrict__ fb2s, const float* __restrict__ S2,
    const int* __restrict__ flags, void* __restrict__ out) {
  int lane = threadIdx.x & 63;
  int wv = threadIdx.x >> 6;
  int m = lane & 15, quad = lane >> 4;
  int bf = flags[1];
  short8x Bf[6];
#pragma unroll
  for (int s = 0; s < 6; ++s) Bf[s] = *(const short8x*)(PK + 12288 + (s * 64 + lane) * 8);
  long long gw = (long long)blockIdx.x * 4 + wv;
  long long nw = (long long)gridDim.x * 4;
  for (long long tile = gw; tile < NT; tile += nw) {
    long long n0 = tile * 16;
    const unsigned short* f2 = F2 + (n0 + m) * 96 + quad * 8;
    short8x A[3];
#pragma unroll
    for (int cc = 0; cc < 3; ++cc) A[cc] = *(const short8x*)(f2 + cc * 32);
    f32x4 acc[2];
#pragma unroll
    for (int t = 0; t < 2; ++t) {
      float b = fb2s[t * 16 + m];
#pragma unroll
      for (int i = 0; i < 4; ++i)
        acc[t][i] = b + S2[(n0 + quad * 4 + i) * 32 + t * 16 + m];
    }
#pragma unroll
    for (int cc = 0; cc < 3; ++cc) {
#pragma unroll
      for (int t = 0; t < 2; ++t)
        acc[t] = __builtin_amdgcn_mfma_f32_16x16x32_bf16(A[cc], Bf[cc * 2 + t], acc[t], 0, 0, 0);
    }
#pragma unroll
    for (int t = 0; t < 2; ++t) {
#pragma unroll
      for (int i = 0; i < 4; ++i) {
        long long idx = (n0 + quad * 4 + i) * 32 + t * 16 + m;
        if (bf) ((unsigned short*)out)[idx] = f2bf(acc[t][i]);
        else ((float*)out)[idx] = acc[t][i];
      }
    }
  }
}

extern "C" void kernel_launch(void* const* d_in, const int* in_sizes, int n_in,
                              void* d_out, int out_size, void* d_ws, size_t ws_size,
                              hipStream_t stream) {
  const void* x = d_in[0];
  const void* ei = d_in[1];
  const void* ea = d_in[2];
  const void* W1_msg = d_in[3];
  const void* b1_msg = d_in[4];
  const void* W1_self = d_in[5];
  const void* b1_self = d_in[6];
  const void* gamma = d_in[7];
  const void* beta = d_in[8];
  const void* mean = d_in[9];
  const void* var = d_in[10];
  const void* W2_msg = d_in[11];
  const void* b2_msg = d_in[12];
  const void* W2_self = d_in[13];
  const void* b2_self = d_in[14];

  float* ws = (float*)d_ws;
  int* counts = (int*)(ws + OFF_CNT);
  int* row_ptr = (int*)(ws + OFF_ROW);
  int2* recs = (int2*)(ws + OFF_RECS);
  int* flags = (int*)(ws + OFF_FLAGS);
  int* bs = (int*)(ws + OFF_BS);
  int* bo = (int*)(ws + OFF_BO);
  unsigned short* PK = (unsigned short*)(ws + OFF_PK);
  float* fb1s = ws + OFF_FB1S;
  float* fb2s = ws + OFF_FB2S;
  unsigned short* F1 = (unsigned short*)(ws + OFF_F1);
  int2* binbuf = (int2*)(ws + OFF_F1);  // aliases F1 (dead before gather1)
  unsigned short* F2 = (unsigned short*)(ws + OFF_F2);
  unsigned short* Y2B = (unsigned short*)(ws + OFF_Y2B);
  float* S2 = ws + OFF_S2;
  int* bcur = (int*)(ws + OFF_BCUR);

  hipLaunchKernelGGL(k_detect, dim3(1), dim3(64), 0, stream, ei, x, flags);
  hipMemsetAsync(bcur, 0, NBK * sizeof(int), stream);
  hipLaunchKernelGGL(k_prep, dim3(64), dim3(256), 0, stream, W1_msg, b1_msg, W1_self,
                     b1_self, gamma, beta, mean, var, W2_msg, b2_msg, W2_self, b2_self,
                     flags, PK, fb1s, fb2s);

  hipLaunchKernelGGL(k_bin, dim3(256), dim3(256), 0, stream, ei, flags, bcur, binbuf);
  hipLaunchKernelGGL(k_bhist, dim3(NBK), dim3(256), 0, stream, bcur, binbuf, counts);
  hipLaunchKernelGGL(k_scanA, dim3(SCB), dim3(1024), 0, stream, counts, bs);
  hipLaunchKernelGGL(k_scanB, dim3(1), dim3(64), 0, stream, bs, bo);
  hipLaunchKernelGGL(k_scanC, dim3(SCB), dim3(1024), 0, stream, counts, bo, row_ptr);
  hipLaunchKernelGGL(k_place, dim3(NBK), dim3(256), 0, stream, bcur, binbuf, row_ptr,
                     recs);

  int gblocks = (NB + 3) / 4;
  hipLaunchKernelGGL(k_gather1, dim3(gblocks), dim3(256), 0, stream, x, ea, row_ptr,
                     recs, flags, F1, F2);
  int mblocks = (NT + 3) / 4;
  hipLaunchKernelGGL(k_gemm1, dim3(mblocks), dim3(256), 0, stream, F1, PK, fb1s, F2);
  hipLaunchKernelGGL(k_gemmY, dim3(mblocks), dim3(256), 0, stream, F2, PK, Y2B);
  hipLaunchKernelGGL(k_gather2, dim3(gblocks), dim3(256), 0, stream, Y2B, row_ptr, recs,
                     S2);
  hipLaunchKernelGGL(k_gemm2, dim3(mblocks), dim3(256), 0, stream, F2, PK, fb2s, S2,
                     flags, d_out);
}